// Round 4
// baseline (464.043 us; speedup 1.0000x reference)
//
#include <hip/hip_runtime.h>
#include <hip/hip_bf16.h>

// Problem constants
constexpr int Bb = 4, Tt = 2048, Dd = 1024, Hh = 16, HD = 64;
constexpr int Mm = Bb * Tt;   // 8192

typedef __attribute__((ext_vector_type(8))) short bf16x8;
typedef __attribute__((ext_vector_type(4))) short s16x4;
typedef __attribute__((ext_vector_type(4))) float f32x4;

__device__ __forceinline__ short f2bf(float f) {
  union { float f; unsigned u; } v; v.f = f;
  unsigned r = (v.u + 0x7fffu + ((v.u >> 16) & 1u)) >> 16;  // RNE
  return (short)r;
}

// ---------------------------------------------------------------- RoPE tables
__global__ void rope_tab(float* __restrict__ cs, float* __restrict__ sn) {
  int idx = blockIdx.x * 256 + threadIdx.x;        // T*HD = 131072
  if (idx >= Tt * HD) return;
  int t = idx >> 6, d = idx & (HD - 1);
  float f = powf(10000.0f, -(float)(d & 31) / 32.0f);
  float ang = (float)t * f;
  cs[idx] = cosf(ang);
  sn[idx] = sinf(ang);
}

// ---------------------------------------------------------------- GEMM
// C[m][n] = sum_k A[m][k] * W[n][k] + bias[n]
// EPI: 0 = Q (RoPE + 0.125 scale, bf16 out [B,H,T,HD])
//      1 = K (RoPE, bf16 out [B,H,T,HD])
//      2 = V (bf16 out [B,H,T,HD])
//      3 = final (fp32 out row-major [M][D])
template<int ABF16, int EPI>
__global__ __launch_bounds__(256) void gemm_k(
    const float* __restrict__ Af, const short* __restrict__ Ab,
    const float* __restrict__ W, const float* __restrict__ bias,
    short* __restrict__ outb, float* __restrict__ outf,
    const float* __restrict__ cs, const float* __restrict__ sn)
{
  constexpr int K = 1024;
  __shared__ short Alds[128][72];
  __shared__ short Blds[128][72];
  const int tid = threadIdx.x;
  const int lane = tid & 63, wave = tid >> 6;
  const int g = lane >> 4, li = lane & 15;
  const int m0 = blockIdx.x * 128, n0 = blockIdx.y * 128;
  const int wm = (wave >> 1) * 64, wn = (wave & 1) * 64;
  f32x4 acc[4][4] = {};

  for (int k0 = 0; k0 < K; k0 += 64) {
    if constexpr (ABF16) {
      #pragma unroll
      for (int s = 0; s < 4; s++) {                 // full 128-row A tile
        int f = tid + s * 256; int row = f >> 3, c8 = f & 7;
        bf16x8 v = *(const bf16x8*)(Ab + (size_t)(m0 + row) * K + k0 + c8 * 8);
        *(bf16x8*)&Alds[row][c8 * 8] = v;
      }
    } else {
      #pragma unroll
      for (int s = 0; s < 8; s++) {
        int f = tid + s * 256; int row = f >> 4, c4 = f & 15;
        float4 v = *(const float4*)(Af + (size_t)(m0 + row) * K + k0 + c4 * 4);
        s16x4 p = { f2bf(v.x), f2bf(v.y), f2bf(v.z), f2bf(v.w) };
        *(s16x4*)&Alds[row][c4 * 4] = p;
      }
    }
    #pragma unroll
    for (int s = 0; s < 8; s++) {
      int f = tid + s * 256; int row = f >> 4, c4 = f & 15;
      float4 v = *(const float4*)(W + (size_t)(n0 + row) * K + k0 + c4 * 4);
      s16x4 p = { f2bf(v.x), f2bf(v.y), f2bf(v.z), f2bf(v.w) };
      *(s16x4*)&Blds[row][c4 * 4] = p;
    }
    __syncthreads();

    bf16x8 af[4][2], bfr[4][2];
    #pragma unroll
    for (int i = 0; i < 4; i++)
      #pragma unroll
      for (int kk = 0; kk < 2; kk++)
        af[i][kk] = *(const bf16x8*)&Alds[wm + i * 16 + li][kk * 32 + g * 8];
    #pragma unroll
    for (int j = 0; j < 4; j++)
      #pragma unroll
      for (int kk = 0; kk < 2; kk++)
        bfr[j][kk] = *(const bf16x8*)&Blds[wn + j * 16 + li][kk * 32 + g * 8];
    #pragma unroll
    for (int i = 0; i < 4; i++)
      #pragma unroll
      for (int j = 0; j < 4; j++)
        #pragma unroll
        for (int kk = 0; kk < 2; kk++)
          acc[i][j] = __builtin_amdgcn_mfma_f32_16x16x32_bf16(
              af[i][kk], bfr[j][kk], acc[i][j], 0, 0, 0);
    __syncthreads();
  }

  // Epilogue
  #pragma unroll
  for (int i = 0; i < 4; i++)
    #pragma unroll
    for (int j = 0; j < 4; j++)
      #pragma unroll
      for (int r = 0; r < 4; r++) {
        int m = m0 + wm + i * 16 + g * 4 + r;
        int n = n0 + wn + j * 16 + li;
        float val = acc[i][j][r] + bias[n];
        if constexpr (EPI == 0 || EPI == 1) {
          float partner = __shfl_xor(val, 1, 64);
          int tt = m & (Tt - 1), hd = n & (HD - 1);
          float c = cs[tt * HD + hd], s = sn[tt * HD + hd];
          float rh = (n & 1) ? partner : -partner;   // rotate_half interleaved
          val = val * c + rh * s;
          if constexpr (EPI == 0) val *= 0.125f;     // 1/sqrt(HD) folded into Q
        }
        if constexpr (EPI <= 2) {
          int bI = m >> 11, tt = m & (Tt - 1), h = n >> 6, hd = n & (HD - 1);
          outb[(((size_t)bI * Hh + h) * Tt + tt) * HD + hd] = f2bf(val);
        } else {
          outf[(size_t)m * Dd + n] = val;
        }
      }
}

// ---------------------------------------------------------------- attention
// grid (T/64, B*H); 4 waves/block, each wave owns 16 q rows; KV tiles of 64.
__global__ __launch_bounds__(256) void attn_k(
    const short* __restrict__ Qb, const short* __restrict__ Kb,
    const short* __restrict__ Vb, short* __restrict__ AO)
{
  __shared__ short Klds[64][72];
  __shared__ short Vt[64][72];
  __shared__ short Plds[4][16][72];
  const int tid = threadIdx.x, lane = tid & 63, wave = tid >> 6;
  const int g = lane >> 4, li = lane & 15;
  const int bh = blockIdx.y;                       // b*H + h
  const int q0 = blockIdx.x * 64 + wave * 16;
  const size_t base = (size_t)bh * Tt * HD;

  bf16x8 qf[2];
  #pragma unroll
  for (int kk = 0; kk < 2; kk++)
    qf[kk] = *(const bf16x8*)(Qb + base + (size_t)(q0 + li) * HD + kk * 32 + g * 8);

  float m_i[4] = { -3.0e38f, -3.0e38f, -3.0e38f, -3.0e38f };
  float l_i[4] = { 0.f, 0.f, 0.f, 0.f };
  f32x4 oacc[4] = {};

  for (int kv0 = 0; kv0 < Tt; kv0 += 64) {
    #pragma unroll
    for (int s = 0; s < 2; s++) {
      int f = tid + s * 256; int row = f >> 3, c8 = f & 7;
      bf16x8 kvv = *(const bf16x8*)(Kb + base + (size_t)(kv0 + row) * HD + c8 * 8);
      *(bf16x8*)&Klds[row][c8 * 8] = kvv;
      bf16x8 vv = *(const bf16x8*)(Vb + base + (size_t)(kv0 + row) * HD + c8 * 8);
      #pragma unroll
      for (int e = 0; e < 8; e++) Vt[c8 * 8 + e][row] = vv[e];  // transpose V
    }
    __syncthreads();

    // S = (Q*0.125) K^T   (scale already folded into Q)
    f32x4 sfr[4];
    #pragma unroll
    for (int cf = 0; cf < 4; cf++) {
      f32x4 z = { 0.f, 0.f, 0.f, 0.f };
      #pragma unroll
      for (int kk = 0; kk < 2; kk++) {
        bf16x8 kf = *(const bf16x8*)&Klds[cf * 16 + li][kk * 32 + g * 8];
        z = __builtin_amdgcn_mfma_f32_16x16x32_bf16(qf[kk], kf, z, 0, 0, 0);
      }
      sfr[cf] = z;
    }

    // online softmax; lane holds rows q = g*4 + r, cols kv = cf*16 + li
    float corr[4];
    #pragma unroll
    for (int r = 0; r < 4; r++) {
      float mv = fmaxf(fmaxf(sfr[0][r], sfr[1][r]), fmaxf(sfr[2][r], sfr[3][r]));
      mv = fmaxf(mv, __shfl_xor(mv, 1, 64));
      mv = fmaxf(mv, __shfl_xor(mv, 2, 64));
      mv = fmaxf(mv, __shfl_xor(mv, 4, 64));
      mv = fmaxf(mv, __shfl_xor(mv, 8, 64));
      float mn = fmaxf(m_i[r], mv);
      corr[r] = __expf(m_i[r] - mn);
      m_i[r] = mn;
    }
    float rs[4] = { 0.f, 0.f, 0.f, 0.f };
    #pragma unroll
    for (int cf = 0; cf < 4; cf++)
      #pragma unroll
      for (int r = 0; r < 4; r++) {
        float p = __expf(sfr[cf][r] - m_i[r]);
        rs[r] += p;
        Plds[wave][g * 4 + r][cf * 16 + li] = f2bf(p);
      }
    #pragma unroll
    for (int r = 0; r < 4; r++) {
      float t = rs[r];
      t += __shfl_xor(t, 1, 64); t += __shfl_xor(t, 2, 64);
      t += __shfl_xor(t, 4, 64); t += __shfl_xor(t, 8, 64);
      l_i[r] = l_i[r] * corr[r] + t;
    }
    #pragma unroll
    for (int hf = 0; hf < 4; hf++)
      #pragma unroll
      for (int r = 0; r < 4; r++)
        oacc[hf][r] *= corr[r];

    // same-wave cross-lane LDS write->read: drain DS queue before P reads
    asm volatile("s_waitcnt lgkmcnt(0)" ::: "memory");
    __builtin_amdgcn_sched_barrier(0);

    // O += P V
    #pragma unroll
    for (int kk = 0; kk < 2; kk++) {
      bf16x8 pa = *(const bf16x8*)&Plds[wave][li][kk * 32 + g * 8];
      #pragma unroll
      for (int hf = 0; hf < 4; hf++) {
        bf16x8 vf = *(const bf16x8*)&Vt[hf * 16 + li][kk * 32 + g * 8];
        oacc[hf] = __builtin_amdgcn_mfma_f32_16x16x32_bf16(pa, vf, oacc[hf], 0, 0, 0);
      }
    }
    __syncthreads();
  }

  const int b = bh >> 4, h = bh & 15;
  #pragma unroll
  for (int hf = 0; hf < 4; hf++)
    #pragma unroll
    for (int r = 0; r < 4; r++) {
      int t = q0 + g * 4 + r;
      float val = oacc[hf][r] / l_i[r];
      AO[((size_t)b * Tt + t) * Dd + h * HD + hf * 16 + li] = f2bf(val);
    }
}

// ---------------------------------------------------------------- launch
extern "C" void kernel_launch(void* const* d_in, const int* in_sizes, int n_in,
                              void* d_out, int out_size, void* d_ws, size_t ws_size,
                              hipStream_t stream)
{
  const float* x  = (const float*)d_in[0];
  const float* Wq = (const float*)d_in[1];
  const float* bq = (const float*)d_in[2];
  const float* Wk = (const float*)d_in[3];
  const float* bk = (const float*)d_in[4];
  const float* Wv = (const float*)d_in[5];
  const float* bv = (const float*)d_in[6];
  const float* Wo = (const float*)d_in[7];
  const float* bo = (const float*)d_in[8];
  float* out = (float*)d_out;

  char* ws = (char*)d_ws;
  float* cs = (float*)ws;                               // 512 KB
  float* sn = (float*)(ws + (size_t)(1 << 19));         // 512 KB
  short* Qb = (short*)(ws + (size_t)(1 << 20));                        // 16 MB
  short* Kb = (short*)(ws + (size_t)(1 << 20) + ((size_t)16 << 20));   // 16 MB
  short* Vb = (short*)(ws + (size_t)(1 << 20) + ((size_t)32 << 20));   // 16 MB
  short* AO = (short*)(ws + (size_t)(1 << 20) + ((size_t)48 << 20));   // 16 MB

  rope_tab<<<dim3(512), dim3(256), 0, stream>>>(cs, sn);

  dim3 gg(Mm / 128, Dd / 128), bb(256);
  gemm_k<0, 0><<<gg, bb, 0, stream>>>(x, nullptr, Wq, bq, Qb, nullptr, cs, sn);
  gemm_k<0, 1><<<gg, bb, 0, stream>>>(x, nullptr, Wk, bk, Kb, nullptr, cs, sn);
  gemm_k<0, 2><<<gg, bb, 0, stream>>>(x, nullptr, Wv, bv, Vb, nullptr, cs, sn);

  attn_k<<<dim3(Tt / 64, Bb * Hh), bb, 0, stream>>>(Qb, Kb, Vb, AO);

  gemm_k<1, 3><<<gg, bb, 0, stream>>>(nullptr, AO, Wo, bo, nullptr, out, cs, sn);
}

// Round 5
// 441.179 us; speedup vs baseline: 1.0518x; 1.0518x over previous
//
#include <hip/hip_runtime.h>
#include <hip/hip_bf16.h>

// Problem constants
constexpr int Bb = 4, Tt = 2048, Dd = 1024, Hh = 16, HD = 64;
constexpr int Mm = Bb * Tt;   // 8192

typedef __attribute__((ext_vector_type(8))) short bf16x8;
typedef __attribute__((ext_vector_type(4))) short s16x4;
typedef __attribute__((ext_vector_type(4))) float f32x4;

__device__ __forceinline__ short f2bf(float f) {
  union { float f; unsigned u; } v; v.f = f;
  unsigned r = (v.u + 0x7fffu + ((v.u >> 16) & 1u)) >> 16;  // RNE
  return (short)r;
}

// ---------------------------------------------------------------- RoPE tables
__global__ void rope_tab(float* __restrict__ cs, float* __restrict__ sn) {
  int idx = blockIdx.x * 256 + threadIdx.x;        // T*HD = 131072
  if (idx >= Tt * HD) return;
  int t = idx >> 6, d = idx & (HD - 1);
  float f = powf(10000.0f, -(float)(d & 31) / 32.0f);
  float ang = (float)t * f;
  cs[idx] = cosf(ang);
  sn[idx] = sinf(ang);
}

// ---------------------------------------------------------------- GEMM
// C[m][n] = sum_k A[m][k] * W[n][k] + bias[n]
// EPI: 0 = Q (RoPE + 0.125*log2e scale, bf16 out [B,H,T,HD])
//      1 = K (RoPE, bf16 out [B,H,T,HD])
//      2 = V (bf16 out TRANSPOSED [B,H,HD,T])
//      3 = final (fp32 out row-major [M][D])
template<int ABF16, int EPI>
__global__ __launch_bounds__(256) void gemm_k(
    const float* __restrict__ Af, const short* __restrict__ Ab,
    const float* __restrict__ W, const float* __restrict__ bias,
    short* __restrict__ outb, float* __restrict__ outf,
    const float* __restrict__ cs, const float* __restrict__ sn)
{
  constexpr int K = 1024;
  __shared__ short Alds[128][72];
  __shared__ short Blds[128][72];
  const int tid = threadIdx.x;
  const int lane = tid & 63, wave = tid >> 6;
  const int g = lane >> 4, li = lane & 15;
  const int m0 = blockIdx.x * 128, n0 = blockIdx.y * 128;
  const int wm = (wave >> 1) * 64, wn = (wave & 1) * 64;
  f32x4 acc[4][4] = {};

  for (int k0 = 0; k0 < K; k0 += 64) {
    if constexpr (ABF16) {
      #pragma unroll
      for (int s = 0; s < 4; s++) {                 // full 128-row A tile
        int f = tid + s * 256; int row = f >> 3, c8 = f & 7;
        bf16x8 v = *(const bf16x8*)(Ab + (size_t)(m0 + row) * K + k0 + c8 * 8);
        *(bf16x8*)&Alds[row][c8 * 8] = v;
      }
    } else {
      #pragma unroll
      for (int s = 0; s < 8; s++) {
        int f = tid + s * 256; int row = f >> 4, c4 = f & 15;
        float4 v = *(const float4*)(Af + (size_t)(m0 + row) * K + k0 + c4 * 4);
        s16x4 p = { f2bf(v.x), f2bf(v.y), f2bf(v.z), f2bf(v.w) };
        *(s16x4*)&Alds[row][c4 * 4] = p;
      }
    }
    #pragma unroll
    for (int s = 0; s < 8; s++) {
      int f = tid + s * 256; int row = f >> 4, c4 = f & 15;
      float4 v = *(const float4*)(W + (size_t)(n0 + row) * K + k0 + c4 * 4);
      s16x4 p = { f2bf(v.x), f2bf(v.y), f2bf(v.z), f2bf(v.w) };
      *(s16x4*)&Blds[row][c4 * 4] = p;
    }
    __syncthreads();

    bf16x8 af[4][2], bfr[4][2];
    #pragma unroll
    for (int i = 0; i < 4; i++)
      #pragma unroll
      for (int kk = 0; kk < 2; kk++)
        af[i][kk] = *(const bf16x8*)&Alds[wm + i * 16 + li][kk * 32 + g * 8];
    #pragma unroll
    for (int j = 0; j < 4; j++)
      #pragma unroll
      for (int kk = 0; kk < 2; kk++)
        bfr[j][kk] = *(const bf16x8*)&Blds[wn + j * 16 + li][kk * 32 + g * 8];
    #pragma unroll
    for (int i = 0; i < 4; i++)
      #pragma unroll
      for (int j = 0; j < 4; j++)
        #pragma unroll
        for (int kk = 0; kk < 2; kk++)
          acc[i][j] = __builtin_amdgcn_mfma_f32_16x16x32_bf16(
              af[i][kk], bfr[j][kk], acc[i][j], 0, 0, 0);
    __syncthreads();
  }

  // Epilogue
  #pragma unroll
  for (int i = 0; i < 4; i++)
    #pragma unroll
    for (int j = 0; j < 4; j++) {
      if constexpr (EPI == 2) {
        // V: transposed store Vt[b,h,d,t]; 4 consecutive t per lane -> 8B pack
        int n = n0 + wn + j * 16 + li;
        s16x4 pk;
        #pragma unroll
        for (int r = 0; r < 4; r++) pk[r] = f2bf(acc[i][j][r] + bias[n]);
        int mb = m0 + wm + i * 16 + g * 4;
        int bI = mb >> 11, t0 = mb & (Tt - 1), h = n >> 6, d = n & (HD - 1);
        *(s16x4*)(outb + (((size_t)bI * Hh + h) * HD + d) * Tt + t0) = pk;
      } else {
        #pragma unroll
        for (int r = 0; r < 4; r++) {
          int m = m0 + wm + i * 16 + g * 4 + r;
          int n = n0 + wn + j * 16 + li;
          float val = acc[i][j][r] + bias[n];
          if constexpr (EPI == 0 || EPI == 1) {
            float partner = __shfl_xor(val, 1, 64);
            int tt = m & (Tt - 1), hd = n & (HD - 1);
            float c = cs[tt * HD + hd], s = sn[tt * HD + hd];
            float rh = (n & 1) ? partner : -partner;   // rotate_half interleaved
            val = val * c + rh * s;
            if constexpr (EPI == 0) val *= 0.18033688f; // 0.125 * log2(e)
          }
          if constexpr (EPI <= 1) {
            int bI = m >> 11, tt = m & (Tt - 1), h = n >> 6, hd = n & (HD - 1);
            outb[(((size_t)bI * Hh + h) * Tt + tt) * HD + hd] = f2bf(val);
          } else {
            outf[(size_t)m * Dd + n] = val;
          }
        }
      }
    }
}

// ---------------------------------------------------------------- attention
// grid (T/128, B*H); 4 waves/block, each wave owns 32 q rows; KV tiles of 64.
// K is [b,h,t,d] (RoPE'd, exp2-scaled Q); V is pre-transposed [b,h,d,t].
__global__ __launch_bounds__(256) void attn_k(
    const short* __restrict__ Qb, const short* __restrict__ Kb,
    const short* __restrict__ Vt_g, short* __restrict__ AO)
{
  __shared__ short Klds[64][72];
  __shared__ short Vt[64][72];      // row = d, col = kv
  __shared__ short Plds[4][32][72];
  const int tid = threadIdx.x, lane = tid & 63, wave = tid >> 6;
  const int g = lane >> 4, li = lane & 15;
  const int bh = blockIdx.y;                       // b*H + h
  const int q0 = blockIdx.x * 128 + wave * 32;
  const size_t base  = (size_t)bh * Tt * HD;       // Q,K layout
  const size_t basev = (size_t)bh * HD * Tt;       // V^T layout

  bf16x8 qf[2][2];
  #pragma unroll
  for (int qi = 0; qi < 2; qi++)
    #pragma unroll
    for (int kk = 0; kk < 2; kk++)
      qf[qi][kk] = *(const bf16x8*)(Qb + base + (size_t)(q0 + qi * 16 + li) * HD + kk * 32 + g * 8);

  float m_i[2][4], l_i[2][4];
  #pragma unroll
  for (int qi = 0; qi < 2; qi++)
    #pragma unroll
    for (int r = 0; r < 4; r++) { m_i[qi][r] = -3.0e38f; l_i[qi][r] = 0.f; }
  f32x4 oacc[2][4] = {};

  for (int kv0 = 0; kv0 < Tt; kv0 += 64) {
    #pragma unroll
    for (int s = 0; s < 2; s++) {
      int f = tid + s * 256; int row = f >> 3, c8 = f & 7;
      *(bf16x8*)&Klds[row][c8 * 8] =
          *(const bf16x8*)(Kb + base + (size_t)(kv0 + row) * HD + c8 * 8);
      *(bf16x8*)&Vt[row][c8 * 8] =
          *(const bf16x8*)(Vt_g + basev + (size_t)row * Tt + kv0 + c8 * 8);
    }
    __syncthreads();

    // S' = (Q * 0.125*log2e) K^T  (exp2 domain)
    f32x4 sfr[2][4];
    #pragma unroll
    for (int qi = 0; qi < 2; qi++)
      #pragma unroll
      for (int cf = 0; cf < 4; cf++) {
        f32x4 z = { 0.f, 0.f, 0.f, 0.f };
        #pragma unroll
        for (int kk = 0; kk < 2; kk++) {
          bf16x8 kf = *(const bf16x8*)&Klds[cf * 16 + li][kk * 32 + g * 8];
          z = __builtin_amdgcn_mfma_f32_16x16x32_bf16(qf[qi][kk], kf, z, 0, 0, 0);
        }
        sfr[qi][cf] = z;
      }

    // online softmax (exp2 domain); lane: rows q = qi*16 + g*4 + r, cols kv = cf*16+li
    #pragma unroll
    for (int qi = 0; qi < 2; qi++) {
      float corr[4];
      #pragma unroll
      for (int r = 0; r < 4; r++) {
        float mv = fmaxf(fmaxf(sfr[qi][0][r], sfr[qi][1][r]),
                         fmaxf(sfr[qi][2][r], sfr[qi][3][r]));
        mv = fmaxf(mv, __shfl_xor(mv, 1, 64));
        mv = fmaxf(mv, __shfl_xor(mv, 2, 64));
        mv = fmaxf(mv, __shfl_xor(mv, 4, 64));
        mv = fmaxf(mv, __shfl_xor(mv, 8, 64));
        float mn = fmaxf(m_i[qi][r], mv);
        corr[r] = exp2f(m_i[qi][r] - mn);
        m_i[qi][r] = mn;
      }
      float rs[4] = { 0.f, 0.f, 0.f, 0.f };
      #pragma unroll
      for (int cf = 0; cf < 4; cf++)
        #pragma unroll
        for (int r = 0; r < 4; r++) {
          float p = exp2f(sfr[qi][cf][r] - m_i[qi][r]);
          rs[r] += p;
          Plds[wave][qi * 16 + g * 4 + r][cf * 16 + li] = f2bf(p);
        }
      #pragma unroll
      for (int r = 0; r < 4; r++) {
        float t = rs[r];
        t += __shfl_xor(t, 1, 64); t += __shfl_xor(t, 2, 64);
        t += __shfl_xor(t, 4, 64); t += __shfl_xor(t, 8, 64);
        l_i[qi][r] = l_i[qi][r] * corr[r] + t;
      }
      #pragma unroll
      for (int hf = 0; hf < 4; hf++)
        #pragma unroll
        for (int r = 0; r < 4; r++)
          oacc[qi][hf][r] *= corr[r];
    }

    // same-wave cross-lane LDS write->read: drain DS queue before P reads
    asm volatile("s_waitcnt lgkmcnt(0)" ::: "memory");
    __builtin_amdgcn_sched_barrier(0);

    // O += P V : A = P[q][kv], B = V[kv][d] read from V^T tile rows (=d)
    #pragma unroll
    for (int qi = 0; qi < 2; qi++)
      #pragma unroll
      for (int kk = 0; kk < 2; kk++) {
        bf16x8 pa = *(const bf16x8*)&Plds[wave][qi * 16 + li][kk * 32 + g * 8];
        #pragma unroll
        for (int hf = 0; hf < 4; hf++) {
          bf16x8 vf = *(const bf16x8*)&Vt[hf * 16 + li][kk * 32 + g * 8];
          oacc[qi][hf] = __builtin_amdgcn_mfma_f32_16x16x32_bf16(pa, vf, oacc[qi][hf], 0, 0, 0);
        }
      }
    __syncthreads();
  }

  const int b = bh >> 4, h = bh & 15;
  #pragma unroll
  for (int qi = 0; qi < 2; qi++)
    #pragma unroll
    for (int hf = 0; hf < 4; hf++)
      #pragma unroll
      for (int r = 0; r < 4; r++) {
        int t = q0 + qi * 16 + g * 4 + r;
        float val = oacc[qi][hf][r] / l_i[qi][r];
        AO[((size_t)b * Tt + t) * Dd + h * HD + hf * 16 + li] = f2bf(val);
      }
}

// ---------------------------------------------------------------- launch
extern "C" void kernel_launch(void* const* d_in, const int* in_sizes, int n_in,
                              void* d_out, int out_size, void* d_ws, size_t ws_size,
                              hipStream_t stream)
{
  const float* x  = (const float*)d_in[0];
  const float* Wq = (const float*)d_in[1];
  const float* bq = (const float*)d_in[2];
  const float* Wk = (const float*)d_in[3];
  const float* bk = (const float*)d_in[4];
  const float* Wv = (const float*)d_in[5];
  const float* bv = (const float*)d_in[6];
  const float* Wo = (const float*)d_in[7];
  const float* bo = (const float*)d_in[8];
  float* out = (float*)d_out;

  char* ws = (char*)d_ws;
  float* cs = (float*)ws;                               // 512 KB
  float* sn = (float*)(ws + (size_t)(1 << 19));         // 512 KB
  short* Qb = (short*)(ws + (size_t)(1 << 20));                        // 16 MB
  short* Kb = (short*)(ws + (size_t)(1 << 20) + ((size_t)16 << 20));   // 16 MB
  short* Vb = (short*)(ws + (size_t)(1 << 20) + ((size_t)32 << 20));   // 16 MB (transposed)
  short* AO = (short*)(ws + (size_t)(1 << 20) + ((size_t)48 << 20));   // 16 MB

  rope_tab<<<dim3(512), dim3(256), 0, stream>>>(cs, sn);

  dim3 gg(Mm / 128, Dd / 128), bb(256);
  gemm_k<0, 0><<<gg, bb, 0, stream>>>(x, nullptr, Wq, bq, Qb, nullptr, cs, sn);
  gemm_k<0, 1><<<gg, bb, 0, stream>>>(x, nullptr, Wk, bk, Kb, nullptr, cs, sn);
  gemm_k<0, 2><<<gg, bb, 0, stream>>>(x, nullptr, Wv, bv, Vb, nullptr, cs, sn);

  attn_k<<<dim3(Tt / 128, Bb * Hh), bb, 0, stream>>>(Qb, Kb, Vb, AO);

  gemm_k<1, 3><<<gg, bb, 0, stream>>>(nullptr, AO, Wo, bo, nullptr, out, cs, sn);
}

// Round 6
// 267.504 us; speedup vs baseline: 1.7347x; 1.6492x over previous
//
#include <hip/hip_runtime.h>
#include <hip/hip_bf16.h>

// Problem constants
constexpr int Bb = 4, Tt = 2048, Dd = 1024, Hh = 16, HD = 64;
constexpr int Mm = Bb * Tt;   // 8192

typedef __attribute__((ext_vector_type(8))) short bf16x8;
typedef __attribute__((ext_vector_type(4))) short s16x4;
typedef __attribute__((ext_vector_type(4))) float f32x4;
typedef __attribute__((ext_vector_type(16))) float f32x16;

__device__ __forceinline__ short f2bf(float f) {
  union { float f; unsigned u; } v; v.f = f;
  unsigned r = (v.u + 0x7fffu + ((v.u >> 16) & 1u)) >> 16;  // RNE
  return (short)r;
}

__device__ __forceinline__ unsigned cvt_pk_bf16(float lo, float hi) {
  unsigned r;
  asm("v_cvt_pk_bf16_f32 %0, %1, %2" : "=v"(r) : "v"(lo), "v"(hi));
  return r;
}

// ---------------------------------------------------------------- RoPE tables
__global__ void rope_tab(float* __restrict__ cs, float* __restrict__ sn) {
  int idx = blockIdx.x * 256 + threadIdx.x;        // T*HD = 131072
  if (idx >= Tt * HD) return;
  int t = idx >> 6, d = idx & (HD - 1);
  float f = powf(10000.0f, -(float)(d & 31) / 32.0f);
  float ang = (float)t * f;
  cs[idx] = cosf(ang);
  sn[idx] = sinf(ang);
}

// ---------------------------------------------------------------- GEMM
// C[m][n] = sum_k A[m][k] * W[n][k] + bias[n]
// EPI: 0 = Q (RoPE + 0.125*log2e scale, bf16 out [B,H,T,HD])
//      1 = K (RoPE, bf16 out [B,H,T,HD])
//      2 = V (bf16 out TRANSPOSED [B,H,HD,T])
//      3 = final (fp32 out row-major [M][D])
template<int ABF16, int EPI>
__global__ __launch_bounds__(256) void gemm_k(
    const float* __restrict__ Af, const short* __restrict__ Ab,
    const float* __restrict__ W, const float* __restrict__ bias,
    short* __restrict__ outb, float* __restrict__ outf,
    const float* __restrict__ cs, const float* __restrict__ sn)
{
  constexpr int K = 1024;
  __shared__ short Alds[128][72];
  __shared__ short Blds[128][72];
  const int tid = threadIdx.x;
  const int lane = tid & 63, wave = tid >> 6;
  const int g = lane >> 4, li = lane & 15;
  const int m0 = blockIdx.x * 128, n0 = blockIdx.y * 128;
  const int wm = (wave >> 1) * 64, wn = (wave & 1) * 64;
  f32x4 acc[4][4] = {};

  for (int k0 = 0; k0 < K; k0 += 64) {
    if constexpr (ABF16) {
      #pragma unroll
      for (int s = 0; s < 4; s++) {                 // full 128-row A tile
        int f = tid + s * 256; int row = f >> 3, c8 = f & 7;
        bf16x8 v = *(const bf16x8*)(Ab + (size_t)(m0 + row) * K + k0 + c8 * 8);
        *(bf16x8*)&Alds[row][c8 * 8] = v;
      }
    } else {
      #pragma unroll
      for (int s = 0; s < 8; s++) {
        int f = tid + s * 256; int row = f >> 4, c4 = f & 15;
        float4 v = *(const float4*)(Af + (size_t)(m0 + row) * K + k0 + c4 * 4);
        s16x4 p = { f2bf(v.x), f2bf(v.y), f2bf(v.z), f2bf(v.w) };
        *(s16x4*)&Alds[row][c4 * 4] = p;
      }
    }
    #pragma unroll
    for (int s = 0; s < 8; s++) {
      int f = tid + s * 256; int row = f >> 4, c4 = f & 15;
      float4 v = *(const float4*)(W + (size_t)(n0 + row) * K + k0 + c4 * 4);
      s16x4 p = { f2bf(v.x), f2bf(v.y), f2bf(v.z), f2bf(v.w) };
      *(s16x4*)&Blds[row][c4 * 4] = p;
    }
    __syncthreads();

    bf16x8 af[4][2], bfr[4][2];
    #pragma unroll
    for (int i = 0; i < 4; i++)
      #pragma unroll
      for (int kk = 0; kk < 2; kk++)
        af[i][kk] = *(const bf16x8*)&Alds[wm + i * 16 + li][kk * 32 + g * 8];
    #pragma unroll
    for (int j = 0; j < 4; j++)
      #pragma unroll
      for (int kk = 0; kk < 2; kk++)
        bfr[j][kk] = *(const bf16x8*)&Blds[wn + j * 16 + li][kk * 32 + g * 8];
    #pragma unroll
    for (int i = 0; i < 4; i++)
      #pragma unroll
      for (int j = 0; j < 4; j++)
        #pragma unroll
        for (int kk = 0; kk < 2; kk++)
          acc[i][j] = __builtin_amdgcn_mfma_f32_16x16x32_bf16(
              af[i][kk], bfr[j][kk], acc[i][j], 0, 0, 0);
    __syncthreads();
  }

  // Epilogue
  #pragma unroll
  for (int i = 0; i < 4; i++)
    #pragma unroll
    for (int j = 0; j < 4; j++) {
      if constexpr (EPI == 2) {
        // V: transposed store Vt[b,h,d,t]; 4 consecutive t per lane -> 8B pack
        int n = n0 + wn + j * 16 + li;
        s16x4 pk;
        #pragma unroll
        for (int r = 0; r < 4; r++) pk[r] = f2bf(acc[i][j][r] + bias[n]);
        int mb = m0 + wm + i * 16 + g * 4;
        int bI = mb >> 11, t0 = mb & (Tt - 1), h = n >> 6, d = n & (HD - 1);
        *(s16x4*)(outb + (((size_t)bI * Hh + h) * HD + d) * Tt + t0) = pk;
      } else {
        #pragma unroll
        for (int r = 0; r < 4; r++) {
          int m = m0 + wm + i * 16 + g * 4 + r;
          int n = n0 + wn + j * 16 + li;
          float val = acc[i][j][r] + bias[n];
          if constexpr (EPI == 0 || EPI == 1) {
            float partner = __shfl_xor(val, 1, 64);
            int tt = m & (Tt - 1), hd = n & (HD - 1);
            float c = cs[tt * HD + hd], s = sn[tt * HD + hd];
            float rh = (n & 1) ? partner : -partner;   // rotate_half interleaved
            val = val * c + rh * s;
            if constexpr (EPI == 0) val *= 0.18033688f; // 0.125 * log2(e)
          }
          if constexpr (EPI <= 1) {
            int bI = m >> 11, tt = m & (Tt - 1), h = n >> 6, hd = n & (HD - 1);
            outb[(((size_t)bI * Hh + h) * Tt + tt) * HD + hd] = f2bf(val);
          } else {
            outf[(size_t)m * Dd + n] = val;
          }
        }
      }
    }
}

// ---------------------------------------------------------------- attention
// Swapped-operand flash attention, 32x32x16 MFMA.
// grid (T/128, B*H); 4 waves/block, each wave owns 32 q rows; KV tiles of 64.
// Q [b,h,t,d] carries 0.125*log2e (exp2 domain); V pre-transposed [b,h,d,t].
// S^T = mfma(K, Q): lane owns full softmax row q = lane&31 (hi half lanes
// duplicate q cols, holding complementary kv slots). O^T = mfma(V^T, P^T).
__device__ __forceinline__ void store_o(const f32x16& o, float inv,
                                        short* __restrict__ AO, size_t rowbase,
                                        int colbase, int h) {
  #pragma unroll
  for (int R = 0; R < 4; R++) {
    s16x4 pk;
    #pragma unroll
    for (int j = 0; j < 4; j++) pk[j] = f2bf(o[R * 4 + j] * inv);
    *(s16x4*)(AO + rowbase + colbase + 8 * R + 4 * h) = pk;
  }
}

__global__ __launch_bounds__(256) void attn_k(
    const short* __restrict__ Qb, const short* __restrict__ Kb,
    const short* __restrict__ Vt_g, short* __restrict__ AO)
{
  __shared__ short Klds[64][72];
  __shared__ short Vt[64][72];      // row = d, col = kv
  const int tid = threadIdx.x, lane = tid & 63, wave = tid >> 6;
  const int h = lane >> 5;          // hi half-wave
  const int ql = lane & 31;         // this lane's q row (and A-frag row idx)
  const int bh = blockIdx.y;        // b*H + h
  const int q0 = blockIdx.x * 128 + wave * 32;
  const size_t base  = (size_t)bh * Tt * HD;   // Q,K layout
  const size_t basev = (size_t)bh * HD * Tt;   // V^T layout

  // Q B-fragments: col=q=lane&31, k = ks*16 + h*8 + e
  bf16x8 qf[4];
  #pragma unroll
  for (int ks = 0; ks < 4; ks++)
    qf[ks] = *(const bf16x8*)(Qb + base + (size_t)(q0 + ql) * HD + ks * 16 + h * 8);

  float m_i = -3.0e38f, l_i = 0.f;
  f32x16 o0 = {}, o1 = {};

  for (int kv0 = 0; kv0 < Tt; kv0 += 64) {
    #pragma unroll
    for (int s = 0; s < 2; s++) {
      int f = tid + s * 256; int row = f >> 3, c8 = f & 7;
      *(bf16x8*)&Klds[row][c8 * 8] =
          *(const bf16x8*)(Kb + base + (size_t)(kv0 + row) * HD + c8 * 8);
      *(bf16x8*)&Vt[row][c8 * 8] =
          *(const bf16x8*)(Vt_g + basev + (size_t)row * Tt + kv0 + c8 * 8);
    }
    __syncthreads();

    // S^T = K · Q^T, two 32-kv tiles. A-frag: row=kv=lane&31, k=ks*16+h*8+e.
    f32x16 st0 = {}, st1 = {};
    #pragma unroll
    for (int ks = 0; ks < 4; ks++) {
      bf16x8 kf0 = *(const bf16x8*)&Klds[ql][ks * 16 + h * 8];
      bf16x8 kf1 = *(const bf16x8*)&Klds[32 + ql][ks * 16 + h * 8];
      st0 = __builtin_amdgcn_mfma_f32_32x32x16_bf16(kf0, qf[ks], st0, 0, 0, 0);
      st1 = __builtin_amdgcn_mfma_f32_32x32x16_bf16(kf1, qf[ks], st1, 0, 0, 0);
    }
    // lane holds S'[kv = kvt*32 + (reg&3)+8*(reg>>2)+4h][q = ql], exp2 domain

    // row max (32 in-lane + pair-lane combine)
    float mv = st0[0];
    #pragma unroll
    for (int r = 1; r < 16; r++) mv = fmaxf(mv, st0[r]);
    #pragma unroll
    for (int r = 0; r < 16; r++) mv = fmaxf(mv, st1[r]);
    mv = fmaxf(mv, __shfl_xor(mv, 32, 64));
    float mn = fmaxf(m_i, mv);
    float corr = __builtin_amdgcn_exp2f(m_i - mn);
    m_i = mn;

    // p = exp2(s - m) in place; row sum
    float rs = 0.f;
    #pragma unroll
    for (int r = 0; r < 16; r++) { st0[r] = __builtin_amdgcn_exp2f(st0[r] - mn); rs += st0[r]; }
    #pragma unroll
    for (int r = 0; r < 16; r++) { st1[r] = __builtin_amdgcn_exp2f(st1[r] - mn); rs += st1[r]; }
    rs += __shfl_xor(rs, 32, 64);
    l_i = l_i * corr + rs;

    #pragma unroll
    for (int r = 0; r < 16; r++) { o0[r] *= corr; o1[r] *= corr; }

    // PV: O^T += V^T · P^T. Per ks build P^T B-frag (col=q, k=ks*16+h*8+e)
    // from in-register p via pair-lane exchange, then 2 MFMAs (d-tiles).
    #pragma unroll
    for (int ks = 0; ks < 4; ks++) {
      const int b0 = ((2 * ks) & 3) * 4;           // 0,8,0,8 (compile-time)
      float A0, A1, A2, A3, B0, B1, B2, B3;
      if (ks < 2) {
        A0 = st0[b0]; A1 = st0[b0 + 1]; A2 = st0[b0 + 2]; A3 = st0[b0 + 3];
        B0 = st0[b0 + 4]; B1 = st0[b0 + 5]; B2 = st0[b0 + 6]; B3 = st0[b0 + 7];
      } else {
        A0 = st1[b0]; A1 = st1[b0 + 1]; A2 = st1[b0 + 2]; A3 = st1[b0 + 3];
        B0 = st1[b0 + 4]; B1 = st1[b0 + 5]; B2 = st1[b0 + 6]; B3 = st1[b0 + 7];
      }
      // A* = group 2ks (e = j+4h), B* = group 2ks+1 (e = j+4h)
      unsigned wa0 = cvt_pk_bf16(A0, A1), wa1 = cvt_pk_bf16(A2, A3);
      unsigned wb0 = cvt_pk_bf16(B0, B1), wb1 = cvt_pk_bf16(B2, B3);
      // send group 2ks+(1-h); receive partner's group 2ks+h (e other half)
      unsigned s0 = h ? wa0 : wb0, s1 = h ? wa1 : wb1;
      unsigned r0 = (unsigned)__shfl_xor((int)s0, 32, 64);
      unsigned r1 = (unsigned)__shfl_xor((int)s1, 32, 64);
      unsigned own0 = h ? wb0 : wa0, own1 = h ? wb1 : wa1;
      union { unsigned u[4]; bf16x8 v; } pa;
      pa.u[0] = h ? r0 : own0;  pa.u[1] = h ? r1 : own1;
      pa.u[2] = h ? own0 : r0;  pa.u[3] = h ? own1 : r1;

      bf16x8 vf0 = *(const bf16x8*)&Vt[ql][ks * 16 + h * 8];
      bf16x8 vf1 = *(const bf16x8*)&Vt[32 + ql][ks * 16 + h * 8];
      o0 = __builtin_amdgcn_mfma_f32_32x32x16_bf16(vf0, pa.v, o0, 0, 0, 0);
      o1 = __builtin_amdgcn_mfma_f32_32x32x16_bf16(vf1, pa.v, o1, 0, 0, 0);
    }
    __syncthreads();
  }

  // epilogue: O^T col = q = ql (per-lane l), row d = nt*32 + (reg&3)+8*(reg>>2)+4h
  float inv = 1.0f / l_i;
  const int b = bh >> 4, hh = bh & 15;
  size_t rowbase = ((size_t)b * Tt + q0 + ql) * Dd;
  store_o(o0, inv, AO, rowbase, hh * 64 + 0, h);
  store_o(o1, inv, AO, rowbase, hh * 64 + 32, h);
}

// ---------------------------------------------------------------- launch
extern "C" void kernel_launch(void* const* d_in, const int* in_sizes, int n_in,
                              void* d_out, int out_size, void* d_ws, size_t ws_size,
                              hipStream_t stream)
{
  const float* x  = (const float*)d_in[0];
  const float* Wq = (const float*)d_in[1];
  const float* bq = (const float*)d_in[2];
  const float* Wk = (const float*)d_in[3];
  const float* bk = (const float*)d_in[4];
  const float* Wv = (const float*)d_in[5];
  const float* bv = (const float*)d_in[6];
  const float* Wo = (const float*)d_in[7];
  const float* bo = (const float*)d_in[8];
  float* out = (float*)d_out;

  char* ws = (char*)d_ws;
  float* cs = (float*)ws;                               // 512 KB
  float* sn = (float*)(ws + (size_t)(1 << 19));         // 512 KB
  short* Qb = (short*)(ws + (size_t)(1 << 20));                        // 16 MB
  short* Kb = (short*)(ws + (size_t)(1 << 20) + ((size_t)16 << 20));   // 16 MB
  short* Vb = (short*)(ws + (size_t)(1 << 20) + ((size_t)32 << 20));   // 16 MB (transposed)
  short* AO = (short*)(ws + (size_t)(1 << 20) + ((size_t)48 << 20));   // 16 MB

  rope_tab<<<dim3(512), dim3(256), 0, stream>>>(cs, sn);

  dim3 gg(Mm / 128, Dd / 128), bb(256);
  gemm_k<0, 0><<<gg, bb, 0, stream>>>(x, nullptr, Wq, bq, Qb, nullptr, cs, sn);
  gemm_k<0, 1><<<gg, bb, 0, stream>>>(x, nullptr, Wk, bk, Kb, nullptr, cs, sn);
  gemm_k<0, 2><<<gg, bb, 0, stream>>>(x, nullptr, Wv, bv, Vb, nullptr, cs, sn);

  attn_k<<<dim3(Tt / 128, Bb * Hh), bb, 0, stream>>>(Qb, Kb, Vb, AO);

  gemm_k<1, 3><<<gg, bb, 0, stream>>>(nullptr, AO, Wo, bo, nullptr, out, cs, sn);
}

// Round 8
// 258.768 us; speedup vs baseline: 1.7933x; 1.0338x over previous
//
#include <hip/hip_runtime.h>
#include <hip/hip_bf16.h>

// Problem constants
constexpr int Bb = 4, Tt = 2048, Dd = 1024, Hh = 16, HD = 64;
constexpr int Mm = Bb * Tt;   // 8192

typedef __attribute__((ext_vector_type(8))) short bf16x8;
typedef __attribute__((ext_vector_type(4))) short s16x4;
typedef __attribute__((ext_vector_type(4))) float f32x4;
typedef __attribute__((ext_vector_type(16))) float f32x16;

__device__ __forceinline__ short f2bf(float f) {
  union { float f; unsigned u; } v; v.f = f;
  unsigned r = (v.u + 0x7fffu + ((v.u >> 16) & 1u)) >> 16;  // RNE
  return (short)r;
}

__device__ __forceinline__ unsigned cvt_pk_bf16(float lo, float hi) {
  unsigned r;
  asm("v_cvt_pk_bf16_f32 %0, %1, %2" : "=v"(r) : "v"(lo), "v"(hi));
  return r;
}

// ---------------------------------------------------------------- fp32 -> bf16 convert
__global__ __launch_bounds__(256) void cvt_k(const float* __restrict__ src,
                                             short* __restrict__ dst, int n4) {
  int i = blockIdx.x * 256 + threadIdx.x;
  if (i >= n4) return;
  float4 v = ((const float4*)src)[i];
  s16x4 p = { f2bf(v.x), f2bf(v.y), f2bf(v.z), f2bf(v.w) };
  ((s16x4*)dst)[i] = p;
}

// ---------------------------------------------------------------- RoPE tables
__global__ void rope_tab(float* __restrict__ cs, float* __restrict__ sn) {
  int idx = blockIdx.x * 256 + threadIdx.x;        // T*HD = 131072
  if (idx >= Tt * HD) return;
  int t = idx >> 6, d = idx & (HD - 1);
  float f = powf(10000.0f, -(float)(d & 31) / 32.0f);
  float ang = (float)t * f;
  cs[idx] = cosf(ang);
  sn[idx] = sinf(ang);
}

// ---------------------------------------------------------------- GEMM
// C[m][n] = sum_k A[m][k] * W[n][k] + bias[n].  A always bf16.
// BF32B: 1 = B operand loaded fp32 and converted during staging.
// EPI: 0 = Q (RoPE + 0.125*log2e scale, bf16 out [B,H,T,HD])
//      1 = K (RoPE, bf16 out [B,H,T,HD])
//      2 = V (bf16 out TRANSPOSED [B,H,HD,T])
//      3 = final (fp32 out row-major [M][D])
template<int EPI, int BF32B>
__global__ __launch_bounds__(256) void gemm_k(
    const short* __restrict__ Ab, const short* __restrict__ Wb,
    const float* __restrict__ Wf, const float* __restrict__ bias,
    short* __restrict__ outb, float* __restrict__ outf,
    const float* __restrict__ cs, const float* __restrict__ sn)
{
  constexpr int K = 1024;
  __shared__ short Alds[128][72];
  __shared__ short Blds[128][72];
  const int tid = threadIdx.x;
  const int lane = tid & 63, wave = tid >> 6;
  const int g = lane >> 4, li = lane & 15;
  const int m0 = blockIdx.x * 128, n0 = blockIdx.y * 128;
  const int wm = (wave >> 1) * 64, wn = (wave & 1) * 64;
  f32x4 acc[4][4] = {};

  for (int k0 = 0; k0 < K; k0 += 64) {
    #pragma unroll
    for (int s = 0; s < 4; s++) {
      int f = tid + s * 256; int row = f >> 3, c8 = f & 7;
      *(bf16x8*)&Alds[row][c8 * 8] =
          *(const bf16x8*)(Ab + (size_t)(m0 + row) * K + k0 + c8 * 8);
    }
    if constexpr (BF32B) {
      #pragma unroll
      for (int s = 0; s < 8; s++) {
        int f = tid + s * 256; int row = f >> 4, c4 = f & 15;
        float4 v = *(const float4*)(Wf + (size_t)(n0 + row) * K + k0 + c4 * 4);
        s16x4 p = { f2bf(v.x), f2bf(v.y), f2bf(v.z), f2bf(v.w) };
        *(s16x4*)&Blds[row][c4 * 4] = p;
      }
    } else {
      #pragma unroll
      for (int s = 0; s < 4; s++) {
        int f = tid + s * 256; int row = f >> 3, c8 = f & 7;
        *(bf16x8*)&Blds[row][c8 * 8] =
            *(const bf16x8*)(Wb + (size_t)(n0 + row) * K + k0 + c8 * 8);
      }
    }
    __syncthreads();

    bf16x8 af[4][2], bfr[4][2];
    #pragma unroll
    for (int i = 0; i < 4; i++)
      #pragma unroll
      for (int kk = 0; kk < 2; kk++)
        af[i][kk] = *(const bf16x8*)&Alds[wm + i * 16 + li][kk * 32 + g * 8];
    #pragma unroll
    for (int j = 0; j < 4; j++)
      #pragma unroll
      for (int kk = 0; kk < 2; kk++)
        bfr[j][kk] = *(const bf16x8*)&Blds[wn + j * 16 + li][kk * 32 + g * 8];
    #pragma unroll
    for (int i = 0; i < 4; i++)
      #pragma unroll
      for (int j = 0; j < 4; j++)
        #pragma unroll
        for (int kk = 0; kk < 2; kk++)
          acc[i][j] = __builtin_amdgcn_mfma_f32_16x16x32_bf16(
              af[i][kk], bfr[j][kk], acc[i][j], 0, 0, 0);
    __syncthreads();
  }

  // Epilogue
  #pragma unroll
  for (int i = 0; i < 4; i++)
    #pragma unroll
    for (int j = 0; j < 4; j++) {
      if constexpr (EPI == 2) {
        // V: transposed store Vt[b,h,d,t]; 4 consecutive t per lane -> 8B pack
        int n = n0 + wn + j * 16 + li;
        s16x4 pk;
        #pragma unroll
        for (int r = 0; r < 4; r++) pk[r] = f2bf(acc[i][j][r] + bias[n]);
        int mb = m0 + wm + i * 16 + g * 4;
        int bI = mb >> 11, t0 = mb & (Tt - 1), h = n >> 6, d = n & (HD - 1);
        *(s16x4*)(outb + (((size_t)bI * Hh + h) * HD + d) * Tt + t0) = pk;
      } else {
        #pragma unroll
        for (int r = 0; r < 4; r++) {
          int m = m0 + wm + i * 16 + g * 4 + r;
          int n = n0 + wn + j * 16 + li;
          float val = acc[i][j][r] + bias[n];
          if constexpr (EPI == 0 || EPI == 1) {
            float partner = __shfl_xor(val, 1, 64);
            int tt = m & (Tt - 1), hd = n & (HD - 1);
            float c = cs[tt * HD + hd], s = sn[tt * HD + hd];
            float rh = (n & 1) ? partner : -partner;   // rotate_half interleaved
            val = val * c + rh * s;
            if constexpr (EPI == 0) val *= 0.18033688f; // 0.125 * log2(e)
          }
          if constexpr (EPI <= 1) {
            int bI = m >> 11, tt = m & (Tt - 1), h = n >> 6, hd = n & (HD - 1);
            outb[(((size_t)bI * Hh + h) * Tt + tt) * HD + hd] = f2bf(val);
          } else {
            outf[(size_t)m * Dd + n] = val;
          }
        }
      }
    }
}

// ---------------------------------------------------------------- attention
// (round-6 version, verbatim — known-good at 130 us)
// Swapped-operand flash attention, 32x32x16 MFMA.
// grid (T/128, B*H); 4 waves/block, each wave owns 32 q rows; KV tiles of 64.
// Q carries 0.125*log2e (exp2 domain); V pre-transposed [b,h,d,t].
__device__ __forceinline__ void store_o(const f32x16& o, float inv,
                                        short* __restrict__ AO, size_t rowbase,
                                        int colbase, int h) {
  #pragma unroll
  for (int R = 0; R < 4; R++) {
    s16x4 pk;
    #pragma unroll
    for (int j = 0; j < 4; j++) pk[j] = f2bf(o[R * 4 + j] * inv);
    *(s16x4*)(AO + rowbase + colbase + 8 * R + 4 * h) = pk;
  }
}

__global__ __launch_bounds__(256) void attn_k(
    const short* __restrict__ Qb, const short* __restrict__ Kb,
    const short* __restrict__ Vt_g, short* __restrict__ AO)
{
  __shared__ short Klds[64][72];
  __shared__ short Vt[64][72];      // row = d, col = kv
  const int tid = threadIdx.x, lane = tid & 63, wave = tid >> 6;
  const int h = lane >> 5;          // hi half-wave
  const int ql = lane & 31;         // this lane's q row (and A-frag row idx)
  const int bh = blockIdx.y;        // b*H + h
  const int q0 = blockIdx.x * 128 + wave * 32;
  const size_t base  = (size_t)bh * Tt * HD;   // Q,K layout
  const size_t basev = (size_t)bh * HD * Tt;   // V^T layout

  // Q B-fragments: col=q=lane&31, k = ks*16 + h*8 + e
  bf16x8 qf[4];
  #pragma unroll
  for (int ks = 0; ks < 4; ks++)
    qf[ks] = *(const bf16x8*)(Qb + base + (size_t)(q0 + ql) * HD + ks * 16 + h * 8);

  float m_i = -3.0e38f, l_i = 0.f;
  f32x16 o0 = {}, o1 = {};

  for (int kv0 = 0; kv0 < Tt; kv0 += 64) {
    #pragma unroll
    for (int s = 0; s < 2; s++) {
      int f = tid + s * 256; int row = f >> 3, c8 = f & 7;
      *(bf16x8*)&Klds[row][c8 * 8] =
          *(const bf16x8*)(Kb + base + (size_t)(kv0 + row) * HD + c8 * 8);
      *(bf16x8*)&Vt[row][c8 * 8] =
          *(const bf16x8*)(Vt_g + basev + (size_t)row * Tt + kv0 + c8 * 8);
    }
    __syncthreads();

    // S^T = K · Q^T, two 32-kv tiles. A-frag: row=kv=lane&31, k=ks*16+h*8+e.
    f32x16 st0 = {}, st1 = {};
    #pragma unroll
    for (int ks = 0; ks < 4; ks++) {
      bf16x8 kf0 = *(const bf16x8*)&Klds[ql][ks * 16 + h * 8];
      bf16x8 kf1 = *(const bf16x8*)&Klds[32 + ql][ks * 16 + h * 8];
      st0 = __builtin_amdgcn_mfma_f32_32x32x16_bf16(kf0, qf[ks], st0, 0, 0, 0);
      st1 = __builtin_amdgcn_mfma_f32_32x32x16_bf16(kf1, qf[ks], st1, 0, 0, 0);
    }
    // lane holds S'[kv = kvt*32 + (reg&3)+8*(reg>>2)+4h][q = ql], exp2 domain

    // row max (32 in-lane + pair-lane combine)
    float mv = st0[0];
    #pragma unroll
    for (int r = 1; r < 16; r++) mv = fmaxf(mv, st0[r]);
    #pragma unroll
    for (int r = 0; r < 16; r++) mv = fmaxf(mv, st1[r]);
    mv = fmaxf(mv, __shfl_xor(mv, 32, 64));
    float mn = fmaxf(m_i, mv);
    float corr = __builtin_amdgcn_exp2f(m_i - mn);
    m_i = mn;

    // p = exp2(s - m) in place; row sum
    float rs = 0.f;
    #pragma unroll
    for (int r = 0; r < 16; r++) { st0[r] = __builtin_amdgcn_exp2f(st0[r] - mn); rs += st0[r]; }
    #pragma unroll
    for (int r = 0; r < 16; r++) { st1[r] = __builtin_amdgcn_exp2f(st1[r] - mn); rs += st1[r]; }
    rs += __shfl_xor(rs, 32, 64);
    l_i = l_i * corr + rs;

    #pragma unroll
    for (int r = 0; r < 16; r++) { o0[r] *= corr; o1[r] *= corr; }

    // PV: O^T += V^T · P^T. Per ks build P^T B-frag (col=q, k=ks*16+h*8+e)
    // from in-register p via pair-lane exchange, then 2 MFMAs (d-tiles).
    #pragma unroll
    for (int ks = 0; ks < 4; ks++) {
      const int b0 = ((2 * ks) & 3) * 4;           // 0,8,0,8 (compile-time)
      float A0, A1, A2, A3, B0, B1, B2, B3;
      if (ks < 2) {
        A0 = st0[b0]; A1 = st0[b0 + 1]; A2 = st0[b0 + 2]; A3 = st0[b0 + 3];
        B0 = st0[b0 + 4]; B1 = st0[b0 + 5]; B2 = st0[b0 + 6]; B3 = st0[b0 + 7];
      } else {
        A0 = st1[b0]; A1 = st1[b0 + 1]; A2 = st1[b0 + 2]; A3 = st1[b0 + 3];
        B0 = st1[b0 + 4]; B1 = st1[b0 + 5]; B2 = st1[b0 + 6]; B3 = st1[b0 + 7];
      }
      // A* = group 2ks (e = j+4h), B* = group 2ks+1 (e = j+4h)
      unsigned wa0 = cvt_pk_bf16(A0, A1), wa1 = cvt_pk_bf16(A2, A3);
      unsigned wb0 = cvt_pk_bf16(B0, B1), wb1 = cvt_pk_bf16(B2, B3);
      // send group 2ks+(1-h); receive partner's group 2ks+h (e other half)
      unsigned s0 = h ? wa0 : wb0, s1 = h ? wa1 : wb1;
      unsigned r0 = (unsigned)__shfl_xor((int)s0, 32, 64);
      unsigned r1 = (unsigned)__shfl_xor((int)s1, 32, 64);
      unsigned own0 = h ? wb0 : wa0, own1 = h ? wb1 : wa1;
      union { unsigned u[4]; bf16x8 v; } pa;
      pa.u[0] = h ? r0 : own0;  pa.u[1] = h ? r1 : own1;
      pa.u[2] = h ? own0 : r0;  pa.u[3] = h ? own1 : r1;

      bf16x8 vf0 = *(const bf16x8*)&Vt[ql][ks * 16 + h * 8];
      bf16x8 vf1 = *(const bf16x8*)&Vt[32 + ql][ks * 16 + h * 8];
      o0 = __builtin_amdgcn_mfma_f32_32x32x16_bf16(vf0, pa.v, o0, 0, 0, 0);
      o1 = __builtin_amdgcn_mfma_f32_32x32x16_bf16(vf1, pa.v, o1, 0, 0, 0);
    }
    __syncthreads();
  }

  // epilogue: O^T col = q = ql (per-lane l), row d = nt*32 + (reg&3)+8*(reg>>2)+4h
  float inv = 1.0f / l_i;
  const int b = bh >> 4, hh = bh & 15;
  size_t rowbase = ((size_t)b * Tt + q0 + ql) * Dd;
  store_o(o0, inv, AO, rowbase, hh * 64 + 0, h);
  store_o(o1, inv, AO, rowbase, hh * 64 + 32, h);
}

// ---------------------------------------------------------------- launch
// ws layout (65 MiB total — proven-safe envelope):
//   [0, 512K)       cs
//   [512K, 1M)      sn
//   1M + [0, 16M)   Qb
//   1M + [16M,32M)  Kb      (Wqb aliases its head before gemm-K; Wob after attn)
//   1M + [32M,48M)  Vb      (Wkb aliases its head before gemm-V)
//   1M + [48M,64M)  xb      (AO aliases after V-GEMM consumed xb)
extern "C" void kernel_launch(void* const* d_in, const int* in_sizes, int n_in,
                              void* d_out, int out_size, void* d_ws, size_t ws_size,
                              hipStream_t stream)
{
  const float* x  = (const float*)d_in[0];
  const float* Wq = (const float*)d_in[1];
  const float* bq = (const float*)d_in[2];
  const float* Wk = (const float*)d_in[3];
  const float* bk = (const float*)d_in[4];
  const float* Wv = (const float*)d_in[5];
  const float* bv = (const float*)d_in[6];
  const float* Wo = (const float*)d_in[7];
  const float* bo = (const float*)d_in[8];
  float* out = (float*)d_out;

  char* ws = (char*)d_ws;
  float* cs = (float*)ws;
  float* sn = (float*)(ws + (size_t)(1 << 19));
  char*  p0 = ws + ((size_t)1 << 20);
  short* Qb = (short*)(p0);
  short* Kb = (short*)(p0 + ((size_t)16 << 20));
  short* Vb = (short*)(p0 + ((size_t)32 << 20));
  short* xb = (short*)(p0 + ((size_t)48 << 20));
  short* AO  = xb;   // xb dead after V-GEMM (last reader)
  short* Wqb = Kb;   // Kb region dead until gemm<1> writes it
  short* Wkb = Vb;   // Vb region dead until gemm<2> writes it
  short* Wob = Kb;   // Kb dead after attn

  cvt_k<<<dim3(Mm * Dd / 4 / 256), dim3(256), 0, stream>>>(x,  xb,  Mm * Dd / 4);
  cvt_k<<<dim3(Dd * Dd / 4 / 256), dim3(256), 0, stream>>>(Wq, Wqb, Dd * Dd / 4);
  cvt_k<<<dim3(Dd * Dd / 4 / 256), dim3(256), 0, stream>>>(Wk, Wkb, Dd * Dd / 4);
  rope_tab<<<dim3(512), dim3(256), 0, stream>>>(cs, sn);

  dim3 gg(Mm / 128, Dd / 128), bb(256);
  gemm_k<0, 0><<<gg, bb, 0, stream>>>(xb, Wqb, nullptr, bq, Qb, nullptr, cs, sn);
  gemm_k<1, 0><<<gg, bb, 0, stream>>>(xb, Wkb, nullptr, bk, Kb, nullptr, cs, sn);
  gemm_k<2, 1><<<gg, bb, 0, stream>>>(xb, nullptr, Wv, bv, Vb, nullptr, cs, sn);

  attn_k<<<dim3(Tt / 128, Bb * Hh), bb, 0, stream>>>(Qb, Kb, Vb, AO);

  cvt_k<<<dim3(Dd * Dd / 4 / 256), dim3(256), 0, stream>>>(Wo, Wob, Dd * Dd / 4);
  gemm_k<3, 0><<<gg, bb, 0, stream>>>(AO, Wob, nullptr, bo, nullptr, out, cs, sn);
}

// Round 10
// 247.407 us; speedup vs baseline: 1.8756x; 1.0459x over previous
//
#include <hip/hip_runtime.h>
#include <hip/hip_bf16.h>

// Problem constants
constexpr int Bb = 4, Tt = 2048, Dd = 1024, Hh = 16, HD = 64;
constexpr int Mm = Bb * Tt;   // 8192

typedef __attribute__((ext_vector_type(8))) short bf16x8;
typedef __attribute__((ext_vector_type(4))) short s16x4;
typedef __attribute__((ext_vector_type(4))) float f32x4;
typedef __attribute__((ext_vector_type(16))) float f32x16;

__device__ __forceinline__ short f2bf(float f) {
  union { float f; unsigned u; } v; v.f = f;
  unsigned r = (v.u + 0x7fffu + ((v.u >> 16) & 1u)) >> 16;  // RNE
  return (short)r;
}

__device__ __forceinline__ unsigned cvt_pk_bf16(float lo, float hi) {
  unsigned r;
  asm("v_cvt_pk_bf16_f32 %0, %1, %2" : "=v"(r) : "v"(lo), "v"(hi));
  return r;
}

// ---------------------------------------------------------------- fp32 -> bf16 convert
__global__ __launch_bounds__(256) void cvt_k(const float* __restrict__ src,
                                             short* __restrict__ dst, int n4) {
  int i = blockIdx.x * 256 + threadIdx.x;
  if (i >= n4) return;
  float4 v = ((const float4*)src)[i];
  s16x4 p = { f2bf(v.x), f2bf(v.y), f2bf(v.z), f2bf(v.w) };
  ((s16x4*)dst)[i] = p;
}

// ---------------------------------------------------------------- RoPE tables
__global__ void rope_tab(float* __restrict__ cs, float* __restrict__ sn) {
  int idx = blockIdx.x * 256 + threadIdx.x;        // T*HD = 131072
  if (idx >= Tt * HD) return;
  int t = idx >> 6, d = idx & (HD - 1);
  float f = powf(10000.0f, -(float)(d & 31) / 32.0f);
  float ang = (float)t * f;
  cs[idx] = cosf(ang);
  sn[idx] = sinf(ang);
}

// ---------------------------------------------------------------- GEMM
// C[m][n] = sum_k A[m][k] * W[n][k] + bias[n].  A always bf16.
// BF32B: 1 = B operand loaded fp32 and converted during staging.
// EPI: 0 = Q (RoPE + 0.125*log2e scale, bf16 out [B,H,T,HD])
//      1 = K (RoPE, bf16 out [B,H,T,HD])
//      2 = V (bf16 out TRANSPOSED [B,H,HD,T])
//      3 = final (fp32 out row-major [M][D])
template<int EPI, int BF32B>
__global__ __launch_bounds__(256) void gemm_k(
    const short* __restrict__ Ab, const short* __restrict__ Wb,
    const float* __restrict__ Wf, const float* __restrict__ bias,
    short* __restrict__ outb, float* __restrict__ outf,
    const float* __restrict__ cs, const float* __restrict__ sn)
{
  constexpr int K = 1024;
  __shared__ short Alds[128][72];
  __shared__ short Blds[128][72];
  const int tid = threadIdx.x;
  const int lane = tid & 63, wave = tid >> 6;
  const int g = lane >> 4, li = lane & 15;
  const int m0 = blockIdx.x * 128, n0 = blockIdx.y * 128;
  const int wm = (wave >> 1) * 64, wn = (wave & 1) * 64;
  f32x4 acc[4][4] = {};

  for (int k0 = 0; k0 < K; k0 += 64) {
    #pragma unroll
    for (int s = 0; s < 4; s++) {
      int f = tid + s * 256; int row = f >> 3, c8 = f & 7;
      *(bf16x8*)&Alds[row][c8 * 8] =
          *(const bf16x8*)(Ab + (size_t)(m0 + row) * K + k0 + c8 * 8);
    }
    if constexpr (BF32B) {
      #pragma unroll
      for (int s = 0; s < 8; s++) {
        int f = tid + s * 256; int row = f >> 4, c4 = f & 15;
        float4 v = *(const float4*)(Wf + (size_t)(n0 + row) * K + k0 + c4 * 4);
        s16x4 p = { f2bf(v.x), f2bf(v.y), f2bf(v.z), f2bf(v.w) };
        *(s16x4*)&Blds[row][c4 * 4] = p;
      }
    } else {
      #pragma unroll
      for (int s = 0; s < 4; s++) {
        int f = tid + s * 256; int row = f >> 3, c8 = f & 7;
        *(bf16x8*)&Blds[row][c8 * 8] =
            *(const bf16x8*)(Wb + (size_t)(n0 + row) * K + k0 + c8 * 8);
      }
    }
    __syncthreads();

    bf16x8 af[4][2], bfr[4][2];
    #pragma unroll
    for (int i = 0; i < 4; i++)
      #pragma unroll
      for (int kk = 0; kk < 2; kk++)
        af[i][kk] = *(const bf16x8*)&Alds[wm + i * 16 + li][kk * 32 + g * 8];
    #pragma unroll
    for (int j = 0; j < 4; j++)
      #pragma unroll
      for (int kk = 0; kk < 2; kk++)
        bfr[j][kk] = *(const bf16x8*)&Blds[wn + j * 16 + li][kk * 32 + g * 8];
    #pragma unroll
    for (int i = 0; i < 4; i++)
      #pragma unroll
      for (int j = 0; j < 4; j++)
        #pragma unroll
        for (int kk = 0; kk < 2; kk++)
          acc[i][j] = __builtin_amdgcn_mfma_f32_16x16x32_bf16(
              af[i][kk], bfr[j][kk], acc[i][j], 0, 0, 0);
    __syncthreads();
  }

  // Epilogue
  #pragma unroll
  for (int i = 0; i < 4; i++)
    #pragma unroll
    for (int j = 0; j < 4; j++) {
      if constexpr (EPI == 2) {
        // V: transposed store Vt[b,h,d,t]; 4 consecutive t per lane -> 8B pack
        int n = n0 + wn + j * 16 + li;
        s16x4 pk;
        #pragma unroll
        for (int r = 0; r < 4; r++) pk[r] = f2bf(acc[i][j][r] + bias[n]);
        int mb = m0 + wm + i * 16 + g * 4;
        int bI = mb >> 11, t0 = mb & (Tt - 1), h = n >> 6, d = n & (HD - 1);
        *(s16x4*)(outb + (((size_t)bI * Hh + h) * HD + d) * Tt + t0) = pk;
      } else {
        #pragma unroll
        for (int r = 0; r < 4; r++) {
          int m = m0 + wm + i * 16 + g * 4 + r;
          int n = n0 + wn + j * 16 + li;
          float val = acc[i][j][r] + bias[n];
          if constexpr (EPI == 0 || EPI == 1) {
            float partner = __shfl_xor(val, 1, 64);
            int tt = m & (Tt - 1), hd = n & (HD - 1);
            float c = cs[tt * HD + hd], s = sn[tt * HD + hd];
            float rh = (n & 1) ? partner : -partner;   // rotate_half interleaved
            val = val * c + rh * s;
            if constexpr (EPI == 0) val *= 0.18033688f; // 0.125 * log2(e)
          }
          if constexpr (EPI <= 1) {
            int bI = m >> 11, tt = m & (Tt - 1), h = n >> 6, hd = n & (HD - 1);
            outb[(((size_t)bI * Hh + h) * Tt + tt) * HD + hd] = f2bf(val);
          } else {
            outf[(size_t)m * Dd + n] = val;
          }
        }
      }
    }
}

// ---------------------------------------------------------------- attention
// Swapped-operand flash attention, 32x32x16 MFMA, 2 waves/block (64 q rows).
// grid (B*H, T/64): all q-blocks of a head land on xcd = bh%8 (K/V L2-local).
// Cross-lane ops are the round-6-proven __shfl_xor(32) forms (no permlane).
// Q carries 0.125*log2e (exp2 domain); V pre-transposed [b,h,d,t].
__device__ __forceinline__ void store_o(const f32x16& o, float inv,
                                        short* __restrict__ AO, size_t rowbase,
                                        int colbase, int h) {
  #pragma unroll
  for (int R = 0; R < 4; R++) {
    s16x4 pk;
    #pragma unroll
    for (int j = 0; j < 4; j++) pk[j] = f2bf(o[R * 4 + j] * inv);
    *(s16x4*)(AO + rowbase + colbase + 8 * R + 4 * h) = pk;
  }
}

__global__ __launch_bounds__(128, 4) void attn_k(
    const short* __restrict__ Qb, const short* __restrict__ Kb,
    const short* __restrict__ Vt_g, short* __restrict__ AO)
{
  __shared__ short Klds[64][72];
  __shared__ short Vt[64][72];      // row = d, col = kv
  const int tid = threadIdx.x, lane = tid & 63, wave = tid >> 6;
  const int h = lane >> 5;          // hi half-wave
  const int ql = lane & 31;         // this lane's q row (and A-frag row idx)
  const int bh = blockIdx.x;        // b*H + h  (fastest dim -> XCD-local K/V)
  const int q0 = blockIdx.y * 64 + wave * 32;
  const size_t base  = (size_t)bh * Tt * HD;   // Q,K layout
  const size_t basev = (size_t)bh * HD * Tt;   // V^T layout

  // Q B-fragments: col=q=lane&31, k = ks*16 + h*8 + e
  bf16x8 qf[4];
  #pragma unroll
  for (int ks = 0; ks < 4; ks++)
    qf[ks] = *(const bf16x8*)(Qb + base + (size_t)(q0 + ql) * HD + ks * 16 + h * 8);

  float m_i = -3.0e38f, l_i = 0.f;
  f32x16 o0 = {}, o1 = {};

  for (int kv0 = 0; kv0 < Tt; kv0 += 64) {
    #pragma unroll
    for (int s = 0; s < 4; s++) {
      int f = tid + s * 128; int row = f >> 3, c8 = f & 7;
      *(bf16x8*)&Klds[row][c8 * 8] =
          *(const bf16x8*)(Kb + base + (size_t)(kv0 + row) * HD + c8 * 8);
      *(bf16x8*)&Vt[row][c8 * 8] =
          *(const bf16x8*)(Vt_g + basev + (size_t)row * Tt + kv0 + c8 * 8);
    }
    __syncthreads();

    // S^T = K · Q^T, two 32-kv tiles. A-frag: row=kv=lane&31, k=ks*16+h*8+e.
    f32x16 st0 = {}, st1 = {};
    __builtin_amdgcn_s_setprio(1);
    #pragma unroll
    for (int ks = 0; ks < 4; ks++) {
      bf16x8 kf0 = *(const bf16x8*)&Klds[ql][ks * 16 + h * 8];
      bf16x8 kf1 = *(const bf16x8*)&Klds[32 + ql][ks * 16 + h * 8];
      st0 = __builtin_amdgcn_mfma_f32_32x32x16_bf16(kf0, qf[ks], st0, 0, 0, 0);
      st1 = __builtin_amdgcn_mfma_f32_32x32x16_bf16(kf1, qf[ks], st1, 0, 0, 0);
    }
    __builtin_amdgcn_s_setprio(0);
    // lane holds S'[kv = kvt*32 + (reg&3)+8*(reg>>2)+4h][q = ql], exp2 domain

    // row max (31 in-lane + cross-half shfl)
    float mv = st0[0];
    #pragma unroll
    for (int r = 1; r < 16; r++) mv = fmaxf(mv, st0[r]);
    #pragma unroll
    for (int r = 0; r < 16; r++) mv = fmaxf(mv, st1[r]);
    mv = fmaxf(mv, __shfl_xor(mv, 32, 64));
    float mn = fmaxf(m_i, mv);
    float corr = __builtin_amdgcn_exp2f(m_i - mn);
    m_i = mn;

    // p = exp2(s - m) in place; row sum
    float rs = 0.f;
    #pragma unroll
    for (int r = 0; r < 16; r++) { st0[r] = __builtin_amdgcn_exp2f(st0[r] - mn); rs += st0[r]; }
    #pragma unroll
    for (int r = 0; r < 16; r++) { st1[r] = __builtin_amdgcn_exp2f(st1[r] - mn); rs += st1[r]; }
    rs += __shfl_xor(rs, 32, 64);
    l_i = l_i * corr + rs;

    #pragma unroll
    for (int r = 0; r < 16; r++) { o0[r] *= corr; o1[r] *= corr; }

    // PV: O^T += V^T · P^T. Per ks build P^T B-frag (col=q, k=ks*16+h*8+e)
    // from in-register p via pair-lane shfl exchange (round-6 proven).
    __builtin_amdgcn_s_setprio(1);
    #pragma unroll
    for (int ks = 0; ks < 4; ks++) {
      const int b0 = ((2 * ks) & 3) * 4;           // 0,8,0,8 (compile-time)
      float A0, A1, A2, A3, B0, B1, B2, B3;
      if (ks < 2) {
        A0 = st0[b0]; A1 = st0[b0 + 1]; A2 = st0[b0 + 2]; A3 = st0[b0 + 3];
        B0 = st0[b0 + 4]; B1 = st0[b0 + 5]; B2 = st0[b0 + 6]; B3 = st0[b0 + 7];
      } else {
        A0 = st1[b0]; A1 = st1[b0 + 1]; A2 = st1[b0 + 2]; A3 = st1[b0 + 3];
        B0 = st1[b0 + 4]; B1 = st1[b0 + 5]; B2 = st1[b0 + 6]; B3 = st1[b0 + 7];
      }
      // A* = group 2ks (e = j+4h), B* = group 2ks+1 (e = j+4h)
      unsigned wa0 = cvt_pk_bf16(A0, A1), wa1 = cvt_pk_bf16(A2, A3);
      unsigned wb0 = cvt_pk_bf16(B0, B1), wb1 = cvt_pk_bf16(B2, B3);
      // send group 2ks+(1-h); receive partner's group 2ks+h (e other half)
      unsigned s0 = h ? wa0 : wb0, s1 = h ? wa1 : wb1;
      unsigned r0 = (unsigned)__shfl_xor((int)s0, 32, 64);
      unsigned r1 = (unsigned)__shfl_xor((int)s1, 32, 64);
      unsigned own0 = h ? wb0 : wa0, own1 = h ? wb1 : wa1;
      union { unsigned u[4]; bf16x8 v; } pa;
      pa.u[0] = h ? r0 : own0;  pa.u[1] = h ? r1 : own1;
      pa.u[2] = h ? own0 : r0;  pa.u[3] = h ? own1 : r1;

      bf16x8 vf0 = *(const bf16x8*)&Vt[ql][ks * 16 + h * 8];
      bf16x8 vf1 = *(const bf16x8*)&Vt[32 + ql][ks * 16 + h * 8];
      o0 = __builtin_amdgcn_mfma_f32_32x32x16_bf16(vf0, pa.v, o0, 0, 0, 0);
      o1 = __builtin_amdgcn_mfma_f32_32x32x16_bf16(vf1, pa.v, o1, 0, 0, 0);
    }
    __builtin_amdgcn_s_setprio(0);
    __syncthreads();
  }

  // epilogue: O^T col = q = ql (per-lane l), row d = nt*32 + (reg&3)+8*(reg>>2)+4h
  float inv = 1.0f / l_i;
  const int b = bh >> 4, hh = bh & 15;
  size_t rowbase = ((size_t)b * Tt + q0 + ql) * Dd;
  store_o(o0, inv, AO, rowbase, hh * 64 + 0, h);
  store_o(o1, inv, AO, rowbase, hh * 64 + 32, h);
}

// ---------------------------------------------------------------- launch
// ws layout (65 MiB total — proven-safe envelope):
//   [0, 512K)       cs
//   [512K, 1M)      sn
//   1M + [0, 16M)   Qb
//   1M + [16M,32M)  Kb      (Wqb aliases its head before gemm-K; Wob after attn)
//   1M + [32M,48M)  Vb      (Wkb aliases its head before gemm-V)
//   1M + [48M,64M)  xb      (AO aliases after V-GEMM consumed xb)
extern "C" void kernel_launch(void* const* d_in, const int* in_sizes, int n_in,
                              void* d_out, int out_size, void* d_ws, size_t ws_size,
                              hipStream_t stream)
{
  const float* x  = (const float*)d_in[0];
  const float* Wq = (const float*)d_in[1];
  const float* bq = (const float*)d_in[2];
  const float* Wk = (const float*)d_in[3];
  const float* bk = (const float*)d_in[4];
  const float* Wv = (const float*)d_in[5];
  const float* bv = (const float*)d_in[6];
  const float* Wo = (const float*)d_in[7];
  const float* bo = (const float*)d_in[8];
  float* out = (float*)d_out;

  char* ws = (char*)d_ws;
  float* cs = (float*)ws;
  float* sn = (float*)(ws + (size_t)(1 << 19));
  char*  p0 = ws + ((size_t)1 << 20);
  short* Qb = (short*)(p0);
  short* Kb = (short*)(p0 + ((size_t)16 << 20));
  short* Vb = (short*)(p0 + ((size_t)32 << 20));
  short* xb = (short*)(p0 + ((size_t)48 << 20));
  short* AO  = xb;   // xb dead after V-GEMM (last reader)
  short* Wqb = Kb;   // Kb region dead until gemm<1> writes it
  short* Wkb = Vb;   // Vb region dead until gemm<2> writes it
  short* Wob = Kb;   // Kb dead after attn

  cvt_k<<<dim3(Mm * Dd / 4 / 256), dim3(256), 0, stream>>>(x,  xb,  Mm * Dd / 4);
  cvt_k<<<dim3(Dd * Dd / 4 / 256), dim3(256), 0, stream>>>(Wq, Wqb, Dd * Dd / 4);
  cvt_k<<<dim3(Dd * Dd / 4 / 256), dim3(256), 0, stream>>>(Wk, Wkb, Dd * Dd / 4);
  rope_tab<<<dim3(512), dim3(256), 0, stream>>>(cs, sn);

  dim3 gg(Mm / 128, Dd / 128), bb(256);
  gemm_k<0, 0><<<gg, bb, 0, stream>>>(xb, Wqb, nullptr, bq, Qb, nullptr, cs, sn);
  gemm_k<1, 0><<<gg, bb, 0, stream>>>(xb, Wkb, nullptr, bk, Kb, nullptr, cs, sn);
  gemm_k<2, 1><<<gg, bb, 0, stream>>>(xb, nullptr, Wv, bv, Vb, nullptr, cs, sn);

  attn_k<<<dim3(Bb * Hh, Tt / 64), dim3(128), 0, stream>>>(Qb, Kb, Vb, AO);

  cvt_k<<<dim3(Dd * Dd / 4 / 256), dim3(256), 0, stream>>>(Wo, Wob, Dd * Dd / 4);
  gemm_k<3, 0><<<gg, bb, 0, stream>>>(AO, Wob, nullptr, bo, nullptr, out, cs, sn);
}

// Round 11
// 232.588 us; speedup vs baseline: 1.9951x; 1.0637x over previous
//
#include <hip/hip_runtime.h>
#include <hip/hip_bf16.h>

// Problem constants
constexpr int Bb = 4, Tt = 2048, Dd = 1024, Hh = 16, HD = 64;
constexpr int Mm = Bb * Tt;   // 8192

typedef __attribute__((ext_vector_type(8))) short bf16x8;
typedef __attribute__((ext_vector_type(4))) short s16x4;
typedef __attribute__((ext_vector_type(4))) float f32x4;
typedef __attribute__((ext_vector_type(16))) float f32x16;

__device__ __forceinline__ short f2bf(float f) {
  union { float f; unsigned u; } v; v.f = f;
  unsigned r = (v.u + 0x7fffu + ((v.u >> 16) & 1u)) >> 16;  // RNE
  return (short)r;
}

__device__ __forceinline__ unsigned cvt_pk_bf16(float lo, float hi) {
  unsigned r;
  asm("v_cvt_pk_bf16_f32 %0, %1, %2" : "=v"(r) : "v"(lo), "v"(hi));
  return r;
}

// async global->LDS, 16B per lane; LDS dest must be wave-uniform base (+lane*16)
__device__ __forceinline__ void gl_lds16(const short* gsrc, short* ldst) {
  __builtin_amdgcn_global_load_lds(
      (const __attribute__((address_space(1))) void*)gsrc,
      (__attribute__((address_space(3))) void*)ldst, 16, 0, 0);
}

// ---------------------------------------------------------------- fp32 -> bf16 convert
__global__ __launch_bounds__(256) void cvt_k(const float* __restrict__ src,
                                             short* __restrict__ dst, int n4) {
  int i = blockIdx.x * 256 + threadIdx.x;
  if (i >= n4) return;
  float4 v = ((const float4*)src)[i];
  s16x4 p = { f2bf(v.x), f2bf(v.y), f2bf(v.z), f2bf(v.w) };
  ((s16x4*)dst)[i] = p;
}

// ---------------------------------------------------------------- RoPE tables
__global__ void rope_tab(float* __restrict__ cs, float* __restrict__ sn) {
  int idx = blockIdx.x * 256 + threadIdx.x;        // T*HD = 131072
  if (idx >= Tt * HD) return;
  int t = idx >> 6, d = idx & (HD - 1);
  float f = powf(10000.0f, -(float)(d & 31) / 32.0f);
  float ang = (float)t * f;
  cs[idx] = cosf(ang);
  sn[idx] = sinf(ang);
}

// ---------------------------------------------------------------- fast GEMM (bf16 x bf16, async staging)
// C[m][n] = sum_k A[m][k] * W[n][k] + bias[n]
// Staging: global_load_lds dwordx4, linear LDS [128][64], source-side XOR swizzle
// (chunk ^= row&7) so fragment ds_read_b128 is 2-way aliased (free).
// EPI: 0 = Q (RoPE + 0.125*log2e, bf16 [B,H,T,HD]); 1 = K (RoPE, bf16 [B,H,T,HD]);
//      3 = final (fp32 [M][D])
template<int EPI>
__global__ __launch_bounds__(256) void gemm_fast(
    const short* __restrict__ Ab, const short* __restrict__ Wb,
    const float* __restrict__ bias,
    short* __restrict__ outb, float* __restrict__ outf,
    const float* __restrict__ cs, const float* __restrict__ sn)
{
  constexpr int K = 1024;
  __shared__ short Alds[128 * 64];
  __shared__ short Blds[128 * 64];
  const int tid = threadIdx.x;
  const int lane = tid & 63, wave = tid >> 6;
  const int g = lane >> 4, li = lane & 15;
  const int m0 = blockIdx.x * 128, n0 = blockIdx.y * 128;
  const int wm = (wave >> 1) * 64, wn = (wave & 1) * 64;
  f32x4 acc[4][4] = {};

  // staging geometry: wave covers rows [wave*32, wave*32+32), 4 issues of 8 rows.
  // lane l -> row_in_group = l>>3, src chunk = (l&7) ^ (l>>3)  (row&7 == l>>3)
  const int lrow = lane >> 3;
  const int soff = lrow * K + (((lane & 7) ^ lrow) * 8);
  const short* Asrc = Ab + (size_t)(m0 + wave * 32) * K + soff;
  const short* Bsrc = Wb + (size_t)(n0 + wave * 32) * K + soff;
  short* Adst = Alds + wave * 32 * 64;
  short* Bdst = Blds + wave * 32 * 64;

  for (int k0 = 0; k0 < K; k0 += 64) {
    #pragma unroll
    for (int i = 0; i < 4; i++) {
      gl_lds16(Asrc + (size_t)i * 8 * K + k0, Adst + i * 8 * 64);
      gl_lds16(Bsrc + (size_t)i * 8 * K + k0, Bdst + i * 8 * 64);
    }
    __syncthreads();   // compiler drains vmcnt before barrier

    bf16x8 af[4][2], bfr[4][2];
    #pragma unroll
    for (int i = 0; i < 4; i++) {
      int row = wm + i * 16 + li, sw = li & 7;
      #pragma unroll
      for (int kk = 0; kk < 2; kk++)
        af[i][kk] = *(const bf16x8*)&Alds[row * 64 + (((kk * 4 + g) ^ sw) * 8)];
    }
    #pragma unroll
    for (int j = 0; j < 4; j++) {
      int row = wn + j * 16 + li, sw = li & 7;
      #pragma unroll
      for (int kk = 0; kk < 2; kk++)
        bfr[j][kk] = *(const bf16x8*)&Blds[row * 64 + (((kk * 4 + g) ^ sw) * 8)];
    }
    #pragma unroll
    for (int i = 0; i < 4; i++)
      #pragma unroll
      for (int j = 0; j < 4; j++)
        #pragma unroll
        for (int kk = 0; kk < 2; kk++)
          acc[i][j] = __builtin_amdgcn_mfma_f32_16x16x32_bf16(
              af[i][kk], bfr[j][kk], acc[i][j], 0, 0, 0);
    __syncthreads();
  }

  // Epilogue (C/D: col = lane&15, row = (lane>>4)*4 + r)
  #pragma unroll
  for (int i = 0; i < 4; i++)
    #pragma unroll
    for (int j = 0; j < 4; j++)
      #pragma unroll
      for (int r = 0; r < 4; r++) {
        int m = m0 + wm + i * 16 + g * 4 + r;
        int n = n0 + wn + j * 16 + li;
        float val = acc[i][j][r] + bias[n];
        if constexpr (EPI == 0 || EPI == 1) {
          float partner = __shfl_xor(val, 1, 64);
          int tt = m & (Tt - 1), hd = n & (HD - 1);
          float c = cs[tt * HD + hd], s = sn[tt * HD + hd];
          float rh = (n & 1) ? partner : -partner;   // rotate_half interleaved
          val = val * c + rh * s;
          if constexpr (EPI == 0) val *= 0.18033688f; // 0.125 * log2(e)
        }
        if constexpr (EPI <= 1) {
          int bI = m >> 11, tt = m & (Tt - 1), h = n >> 6, hd = n & (HD - 1);
          outb[(((size_t)bI * Hh + h) * Tt + tt) * HD + hd] = f2bf(val);
        } else {
          outf[(size_t)m * Dd + n] = val;
        }
      }
}

// ---------------------------------------------------------------- V GEMM (bf16 A, fp32 B, reg staging)
// EPI=2 semantics: V output bf16 TRANSPOSED [B,H,HD,T]
__global__ __launch_bounds__(256) void gemm_v(
    const short* __restrict__ Ab, const float* __restrict__ Wf,
    const float* __restrict__ bias, short* __restrict__ outb)
{
  constexpr int K = 1024;
  __shared__ short Alds[128][72];
  __shared__ short Blds[128][72];
  const int tid = threadIdx.x;
  const int lane = tid & 63, wave = tid >> 6;
  const int g = lane >> 4, li = lane & 15;
  const int m0 = blockIdx.x * 128, n0 = blockIdx.y * 128;
  const int wm = (wave >> 1) * 64, wn = (wave & 1) * 64;
  f32x4 acc[4][4] = {};

  for (int k0 = 0; k0 < K; k0 += 64) {
    #pragma unroll
    for (int s = 0; s < 4; s++) {
      int f = tid + s * 256; int row = f >> 3, c8 = f & 7;
      *(bf16x8*)&Alds[row][c8 * 8] =
          *(const bf16x8*)(Ab + (size_t)(m0 + row) * K + k0 + c8 * 8);
    }
    #pragma unroll
    for (int s = 0; s < 8; s++) {
      int f = tid + s * 256; int row = f >> 4, c4 = f & 15;
      float4 v = *(const float4*)(Wf + (size_t)(n0 + row) * K + k0 + c4 * 4);
      s16x4 p = { f2bf(v.x), f2bf(v.y), f2bf(v.z), f2bf(v.w) };
      *(s16x4*)&Blds[row][c4 * 4] = p;
    }
    __syncthreads();

    bf16x8 af[4][2], bfr[4][2];
    #pragma unroll
    for (int i = 0; i < 4; i++)
      #pragma unroll
      for (int kk = 0; kk < 2; kk++)
        af[i][kk] = *(const bf16x8*)&Alds[wm + i * 16 + li][kk * 32 + g * 8];
    #pragma unroll
    for (int j = 0; j < 4; j++)
      #pragma unroll
      for (int kk = 0; kk < 2; kk++)
        bfr[j][kk] = *(const bf16x8*)&Blds[wn + j * 16 + li][kk * 32 + g * 8];
    #pragma unroll
    for (int i = 0; i < 4; i++)
      #pragma unroll
      for (int j = 0; j < 4; j++)
        #pragma unroll
        for (int kk = 0; kk < 2; kk++)
          acc[i][j] = __builtin_amdgcn_mfma_f32_16x16x32_bf16(
              af[i][kk], bfr[j][kk], acc[i][j], 0, 0, 0);
    __syncthreads();
  }

  #pragma unroll
  for (int i = 0; i < 4; i++)
    #pragma unroll
    for (int j = 0; j < 4; j++) {
      // transposed store Vt[b,h,d,t]; 4 consecutive t per lane -> 8B pack
      int n = n0 + wn + j * 16 + li;
      s16x4 pk;
      #pragma unroll
      for (int r = 0; r < 4; r++) pk[r] = f2bf(acc[i][j][r] + bias[n]);
      int mb = m0 + wm + i * 16 + g * 4;
      int bI = mb >> 11, t0 = mb & (Tt - 1), h = n >> 6, d = n & (HD - 1);
      *(s16x4*)(outb + (((size_t)bI * Hh + h) * HD + d) * Tt + t0) = pk;
    }
}

// ---------------------------------------------------------------- attention
// (round-10 version, verbatim — known-good at 110 us)
// Swapped-operand flash attention, 32x32x16 MFMA, 2 waves/block (64 q rows).
// grid (B*H, T/64): all q-blocks of a head land on xcd = bh%8 (K/V L2-local).
// Q carries 0.125*log2e (exp2 domain); V pre-transposed [b,h,d,t].
__device__ __forceinline__ void store_o(const f32x16& o, float inv,
                                        short* __restrict__ AO, size_t rowbase,
                                        int colbase, int h) {
  #pragma unroll
  for (int R = 0; R < 4; R++) {
    s16x4 pk;
    #pragma unroll
    for (int j = 0; j < 4; j++) pk[j] = f2bf(o[R * 4 + j] * inv);
    *(s16x4*)(AO + rowbase + colbase + 8 * R + 4 * h) = pk;
  }
}

__global__ __launch_bounds__(128, 4) void attn_k(
    const short* __restrict__ Qb, const short* __restrict__ Kb,
    const short* __restrict__ Vt_g, short* __restrict__ AO)
{
  __shared__ short Klds[64][72];
  __shared__ short Vt[64][72];      // row = d, col = kv
  const int tid = threadIdx.x, lane = tid & 63, wave = tid >> 6;
  const int h = lane >> 5;          // hi half-wave
  const int ql = lane & 31;         // this lane's q row (and A-frag row idx)
  const int bh = blockIdx.x;        // b*H + h  (fastest dim -> XCD-local K/V)
  const int q0 = blockIdx.y * 64 + wave * 32;
  const size_t base  = (size_t)bh * Tt * HD;   // Q,K layout
  const size_t basev = (size_t)bh * HD * Tt;   // V^T layout

  // Q B-fragments: col=q=lane&31, k = ks*16 + h*8 + e
  bf16x8 qf[4];
  #pragma unroll
  for (int ks = 0; ks < 4; ks++)
    qf[ks] = *(const bf16x8*)(Qb + base + (size_t)(q0 + ql) * HD + ks * 16 + h * 8);

  float m_i = -3.0e38f, l_i = 0.f;
  f32x16 o0 = {}, o1 = {};

  for (int kv0 = 0; kv0 < Tt; kv0 += 64) {
    #pragma unroll
    for (int s = 0; s < 4; s++) {
      int f = tid + s * 128; int row = f >> 3, c8 = f & 7;
      *(bf16x8*)&Klds[row][c8 * 8] =
          *(const bf16x8*)(Kb + base + (size_t)(kv0 + row) * HD + c8 * 8);
      *(bf16x8*)&Vt[row][c8 * 8] =
          *(const bf16x8*)(Vt_g + basev + (size_t)row * Tt + kv0 + c8 * 8);
    }
    __syncthreads();

    // S^T = K · Q^T, two 32-kv tiles. A-frag: row=kv=lane&31, k=ks*16+h*8+e.
    f32x16 st0 = {}, st1 = {};
    __builtin_amdgcn_s_setprio(1);
    #pragma unroll
    for (int ks = 0; ks < 4; ks++) {
      bf16x8 kf0 = *(const bf16x8*)&Klds[ql][ks * 16 + h * 8];
      bf16x8 kf1 = *(const bf16x8*)&Klds[32 + ql][ks * 16 + h * 8];
      st0 = __builtin_amdgcn_mfma_f32_32x32x16_bf16(kf0, qf[ks], st0, 0, 0, 0);
      st1 = __builtin_amdgcn_mfma_f32_32x32x16_bf16(kf1, qf[ks], st1, 0, 0, 0);
    }
    __builtin_amdgcn_s_setprio(0);
    // lane holds S'[kv = kvt*32 + (reg&3)+8*(reg>>2)+4h][q = ql], exp2 domain

    // row max (31 in-lane + cross-half shfl)
    float mv = st0[0];
    #pragma unroll
    for (int r = 1; r < 16; r++) mv = fmaxf(mv, st0[r]);
    #pragma unroll
    for (int r = 0; r < 16; r++) mv = fmaxf(mv, st1[r]);
    mv = fmaxf(mv, __shfl_xor(mv, 32, 64));
    float mn = fmaxf(m_i, mv);
    float corr = __builtin_amdgcn_exp2f(m_i - mn);
    m_i = mn;

    // p = exp2(s - m) in place; row sum
    float rs = 0.f;
    #pragma unroll
    for (int r = 0; r < 16; r++) { st0[r] = __builtin_amdgcn_exp2f(st0[r] - mn); rs += st0[r]; }
    #pragma unroll
    for (int r = 0; r < 16; r++) { st1[r] = __builtin_amdgcn_exp2f(st1[r] - mn); rs += st1[r]; }
    rs += __shfl_xor(rs, 32, 64);
    l_i = l_i * corr + rs;

    #pragma unroll
    for (int r = 0; r < 16; r++) { o0[r] *= corr; o1[r] *= corr; }

    // PV: O^T += V^T · P^T. Per ks build P^T B-frag (col=q, k=ks*16+h*8+e)
    // from in-register p via pair-lane shfl exchange (round-6 proven).
    __builtin_amdgcn_s_setprio(1);
    #pragma unroll
    for (int ks = 0; ks < 4; ks++) {
      const int b0 = ((2 * ks) & 3) * 4;           // 0,8,0,8 (compile-time)
      float A0, A1, A2, A3, B0, B1, B2, B3;
      if (ks < 2) {
        A0 = st0[b0]; A1 = st0[b0 + 1]; A2 = st0[b0 + 2]; A3 = st0[b0 + 3];
        B0 = st0[b0 + 4]; B1 = st0[b0 + 5]; B2 = st0[b0 + 6]; B3 = st0[b0 + 7];
      } else {
        A0 = st1[b0]; A1 = st1[b0 + 1]; A2 = st1[b0 + 2]; A3 = st1[b0 + 3];
        B0 = st1[b0 + 4]; B1 = st1[b0 + 5]; B2 = st1[b0 + 6]; B3 = st1[b0 + 7];
      }
      // A* = group 2ks (e = j+4h), B* = group 2ks+1 (e = j+4h)
      unsigned wa0 = cvt_pk_bf16(A0, A1), wa1 = cvt_pk_bf16(A2, A3);
      unsigned wb0 = cvt_pk_bf16(B0, B1), wb1 = cvt_pk_bf16(B2, B3);
      // send group 2ks+(1-h); receive partner's group 2ks+h (e other half)
      unsigned s0 = h ? wa0 : wb0, s1 = h ? wa1 : wb1;
      unsigned r0 = (unsigned)__shfl_xor((int)s0, 32, 64);
      unsigned r1 = (unsigned)__shfl_xor((int)s1, 32, 64);
      unsigned own0 = h ? wb0 : wa0, own1 = h ? wb1 : wa1;
      union { unsigned u[4]; bf16x8 v; } pa;
      pa.u[0] = h ? r0 : own0;  pa.u[1] = h ? r1 : own1;
      pa.u[2] = h ? own0 : r0;  pa.u[3] = h ? own1 : r1;

      bf16x8 vf0 = *(const bf16x8*)&Vt[ql][ks * 16 + h * 8];
      bf16x8 vf1 = *(const bf16x8*)&Vt[32 + ql][ks * 16 + h * 8];
      o0 = __builtin_amdgcn_mfma_f32_32x32x16_bf16(vf0, pa.v, o0, 0, 0, 0);
      o1 = __builtin_amdgcn_mfma_f32_32x32x16_bf16(vf1, pa.v, o1, 0, 0, 0);
    }
    __builtin_amdgcn_s_setprio(0);
    __syncthreads();
  }

  // epilogue: O^T col = q = ql (per-lane l), row d = nt*32 + (reg&3)+8*(reg>>2)+4h
  float inv = 1.0f / l_i;
  const int b = bh >> 4, hh = bh & 15;
  size_t rowbase = ((size_t)b * Tt + q0 + ql) * Dd;
  store_o(o0, inv, AO, rowbase, hh * 64 + 0, h);
  store_o(o1, inv, AO, rowbase, hh * 64 + 32, h);
}

// ---------------------------------------------------------------- launch
// ws layout (65 MiB total — proven-safe envelope):
//   [0, 512K)       cs
//   [512K, 1M)      sn
//   1M + [0, 16M)   Qb
//   1M + [16M,32M)  Kb      (Wqb aliases its head before gemm-K; Wob after attn)
//   1M + [32M,48M)  Vb      (Wkb aliases its head before gemm-V)
//   1M + [48M,64M)  xb      (AO aliases after V-GEMM consumed xb)
extern "C" void kernel_launch(void* const* d_in, const int* in_sizes, int n_in,
                              void* d_out, int out_size, void* d_ws, size_t ws_size,
                              hipStream_t stream)
{
  const float* x  = (const float*)d_in[0];
  const float* Wq = (const float*)d_in[1];
  const float* bq = (const float*)d_in[2];
  const float* Wk = (const float*)d_in[3];
  const float* bk = (const float*)d_in[4];
  const float* Wv = (const float*)d_in[5];
  const float* bv = (const float*)d_in[6];
  const float* Wo = (const float*)d_in[7];
  const float* bo = (const float*)d_in[8];
  float* out = (float*)d_out;

  char* ws = (char*)d_ws;
  float* cs = (float*)ws;
  float* sn = (float*)(ws + (size_t)(1 << 19));
  char*  p0 = ws + ((size_t)1 << 20);
  short* Qb = (short*)(p0);
  short* Kb = (short*)(p0 + ((size_t)16 << 20));
  short* Vb = (short*)(p0 + ((size_t)32 << 20));
  short* xb = (short*)(p0 + ((size_t)48 << 20));
  short* AO  = xb;   // xb dead after V-GEMM (last reader)
  short* Wqb = Kb;   // Kb region dead until gemm<1> writes it
  short* Wkb = Vb;   // Vb region dead until gemm_v writes it
  short* Wob = Kb;   // Kb dead after attn

  cvt_k<<<dim3(Mm * Dd / 4 / 256), dim3(256), 0, stream>>>(x,  xb,  Mm * Dd / 4);
  cvt_k<<<dim3(Dd * Dd / 4 / 256), dim3(256), 0, stream>>>(Wq, Wqb, Dd * Dd / 4);
  cvt_k<<<dim3(Dd * Dd / 4 / 256), dim3(256), 0, stream>>>(Wk, Wkb, Dd * Dd / 4);
  rope_tab<<<dim3(512), dim3(256), 0, stream>>>(cs, sn);

  dim3 gg(Mm / 128, Dd / 128), bb(256);
  gemm_fast<0><<<gg, bb, 0, stream>>>(xb, Wqb, bq, Qb, nullptr, cs, sn);
  gemm_fast<1><<<gg, bb, 0, stream>>>(xb, Wkb, bk, Kb, nullptr, cs, sn);
  gemm_v<<<gg, bb, 0, stream>>>(xb, Wv, bv, Vb);

  attn_k<<<dim3(Bb * Hh, Tt / 64), dim3(128), 0, stream>>>(Qb, Kb, Vb, AO);

  cvt_k<<<dim3(Dd * Dd / 4 / 256), dim3(256), 0, stream>>>(Wo, Wob, Dd * Dd / 4);
  gemm_fast<3><<<gg, bb, 0, stream>>>(AO, Wob, bo, nullptr, out, cs, sn);
}

// Round 12
// 224.358 us; speedup vs baseline: 2.0683x; 1.0367x over previous
//
#include <hip/hip_runtime.h>
#include <hip/hip_bf16.h>

// Problem constants
constexpr int Bb = 4, Tt = 2048, Dd = 1024, Hh = 16, HD = 64;
constexpr int Mm = Bb * Tt;   // 8192

typedef __attribute__((ext_vector_type(8))) short bf16x8;
typedef __attribute__((ext_vector_type(4))) short s16x4;
typedef __attribute__((ext_vector_type(4))) float f32x4;
typedef __attribute__((ext_vector_type(16))) float f32x16;

__device__ __forceinline__ short f2bf(float f) {
  union { float f; unsigned u; } v; v.f = f;
  unsigned r = (v.u + 0x7fffu + ((v.u >> 16) & 1u)) >> 16;  // RNE
  return (short)r;
}

__device__ __forceinline__ unsigned cvt_pk_bf16(float lo, float hi) {
  unsigned r;
  asm("v_cvt_pk_bf16_f32 %0, %1, %2" : "=v"(r) : "v"(lo), "v"(hi));
  return r;
}

__device__ __forceinline__ float max3f(float a, float b, float c) {
  float d;
  asm("v_max3_f32 %0, %1, %2, %3" : "=v"(d) : "v"(a), "v"(b), "v"(c));
  return d;
}

// async global->LDS, 16B per lane; LDS dest must be wave-uniform base (+lane*16)
__device__ __forceinline__ void gl_lds16(const short* gsrc, short* ldst) {
  __builtin_amdgcn_global_load_lds(
      (const __attribute__((address_space(1))) void*)gsrc,
      (__attribute__((address_space(3))) void*)ldst, 16, 0, 0);
}

// ---------------------------------------------------------------- fp32 -> bf16 convert
__global__ __launch_bounds__(256) void cvt_k(const float* __restrict__ src,
                                             short* __restrict__ dst, int n4) {
  int i = blockIdx.x * 256 + threadIdx.x;
  if (i >= n4) return;
  float4 v = ((const float4*)src)[i];
  s16x4 p = { f2bf(v.x), f2bf(v.y), f2bf(v.z), f2bf(v.w) };
  ((s16x4*)dst)[i] = p;
}

// ---------------------------------------------------------------- RoPE tables
__global__ void rope_tab(float* __restrict__ cs, float* __restrict__ sn) {
  int idx = blockIdx.x * 256 + threadIdx.x;        // T*HD = 131072
  if (idx >= Tt * HD) return;
  int t = idx >> 6, d = idx & (HD - 1);
  float f = powf(10000.0f, -(float)(d & 31) / 32.0f);
  float ang = (float)t * f;
  cs[idx] = cosf(ang);
  sn[idx] = sinf(ang);
}

// ---------------------------------------------------------------- fused Q+K GEMM
// blockIdx.z: 0 = Q (RoPE + 0.125*log2e), 1 = K (RoPE). bf16 out [B,H,T,HD].
// Staging: global_load_lds dwordx4, linear LDS, source-side XOR swizzle.
__global__ __launch_bounds__(256) void gemm_qk(
    const short* __restrict__ Ab,
    const short* __restrict__ Wqb, const short* __restrict__ Wkb,
    const float* __restrict__ bq, const float* __restrict__ bk,
    short* __restrict__ Qo, short* __restrict__ Ko,
    const float* __restrict__ cs, const float* __restrict__ sn)
{
  constexpr int K = 1024;
  __shared__ short Alds[128 * 64];
  __shared__ short Blds[128 * 64];
  const bool isQ = (blockIdx.z == 0);
  const short* Wb = isQ ? Wqb : Wkb;
  const float* bias = isQ ? bq : bk;
  short* outb = isQ ? Qo : Ko;
  const float scale = isQ ? 0.18033688f : 1.0f;   // 0.125 * log2(e) for Q

  const int tid = threadIdx.x;
  const int lane = tid & 63, wave = tid >> 6;
  const int g = lane >> 4, li = lane & 15;
  const int m0 = blockIdx.x * 128, n0 = blockIdx.y * 128;
  const int wm = (wave >> 1) * 64, wn = (wave & 1) * 64;
  f32x4 acc[4][4] = {};

  const int lrow = lane >> 3;
  const int soff = lrow * K + (((lane & 7) ^ lrow) * 8);
  const short* Asrc = Ab + (size_t)(m0 + wave * 32) * K + soff;
  const short* Bsrc = Wb + (size_t)(n0 + wave * 32) * K + soff;
  short* Adst = Alds + wave * 32 * 64;
  short* Bdst = Blds + wave * 32 * 64;

  for (int k0 = 0; k0 < K; k0 += 64) {
    #pragma unroll
    for (int i = 0; i < 4; i++) {
      gl_lds16(Asrc + (size_t)i * 8 * K + k0, Adst + i * 8 * 64);
      gl_lds16(Bsrc + (size_t)i * 8 * K + k0, Bdst + i * 8 * 64);
    }
    __syncthreads();

    bf16x8 af[4][2], bfr[4][2];
    #pragma unroll
    for (int i = 0; i < 4; i++) {
      int row = wm + i * 16 + li, sw = li & 7;
      #pragma unroll
      for (int kk = 0; kk < 2; kk++)
        af[i][kk] = *(const bf16x8*)&Alds[row * 64 + (((kk * 4 + g) ^ sw) * 8)];
    }
    #pragma unroll
    for (int j = 0; j < 4; j++) {
      int row = wn + j * 16 + li, sw = li & 7;
      #pragma unroll
      for (int kk = 0; kk < 2; kk++)
        bfr[j][kk] = *(const bf16x8*)&Blds[row * 64 + (((kk * 4 + g) ^ sw) * 8)];
    }
    #pragma unroll
    for (int i = 0; i < 4; i++)
      #pragma unroll
      for (int j = 0; j < 4; j++)
        #pragma unroll
        for (int kk = 0; kk < 2; kk++)
          acc[i][j] = __builtin_amdgcn_mfma_f32_16x16x32_bf16(
              af[i][kk], bfr[j][kk], acc[i][j], 0, 0, 0);
    __syncthreads();
  }

  #pragma unroll
  for (int i = 0; i < 4; i++)
    #pragma unroll
    for (int j = 0; j < 4; j++)
      #pragma unroll
      for (int r = 0; r < 4; r++) {
        int m = m0 + wm + i * 16 + g * 4 + r;
        int n = n0 + wn + j * 16 + li;
        float val = acc[i][j][r] + bias[n];
        float partner = __shfl_xor(val, 1, 64);
        int tt = m & (Tt - 1), hd = n & (HD - 1);
        float c = cs[tt * HD + hd], s = sn[tt * HD + hd];
        float rh = (n & 1) ? partner : -partner;   // rotate_half interleaved
        val = (val * c + rh * s) * scale;
        int bI = m >> 11, h = n >> 6;
        outb[(((size_t)bI * Hh + h) * Tt + tt) * HD + hd] = f2bf(val);
      }
}

// ---------------------------------------------------------------- final GEMM (bf16 x bf16, fp32 out)
__global__ __launch_bounds__(256) void gemm_fin(
    const short* __restrict__ Ab, const short* __restrict__ Wb,
    const float* __restrict__ bias, float* __restrict__ outf)
{
  constexpr int K = 1024;
  __shared__ short Alds[128 * 64];
  __shared__ short Blds[128 * 64];
  const int tid = threadIdx.x;
  const int lane = tid & 63, wave = tid >> 6;
  const int g = lane >> 4, li = lane & 15;
  const int m0 = blockIdx.x * 128, n0 = blockIdx.y * 128;
  const int wm = (wave >> 1) * 64, wn = (wave & 1) * 64;
  f32x4 acc[4][4] = {};

  const int lrow = lane >> 3;
  const int soff = lrow * K + (((lane & 7) ^ lrow) * 8);
  const short* Asrc = Ab + (size_t)(m0 + wave * 32) * K + soff;
  const short* Bsrc = Wb + (size_t)(n0 + wave * 32) * K + soff;
  short* Adst = Alds + wave * 32 * 64;
  short* Bdst = Blds + wave * 32 * 64;

  for (int k0 = 0; k0 < K; k0 += 64) {
    #pragma unroll
    for (int i = 0; i < 4; i++) {
      gl_lds16(Asrc + (size_t)i * 8 * K + k0, Adst + i * 8 * 64);
      gl_lds16(Bsrc + (size_t)i * 8 * K + k0, Bdst + i * 8 * 64);
    }
    __syncthreads();

    bf16x8 af[4][2], bfr[4][2];
    #pragma unroll
    for (int i = 0; i < 4; i++) {
      int row = wm + i * 16 + li, sw = li & 7;
      #pragma unroll
      for (int kk = 0; kk < 2; kk++)
        af[i][kk] = *(const bf16x8*)&Alds[row * 64 + (((kk * 4 + g) ^ sw) * 8)];
    }
    #pragma unroll
    for (int j = 0; j < 4; j++) {
      int row = wn + j * 16 + li, sw = li & 7;
      #pragma unroll
      for (int kk = 0; kk < 2; kk++)
        bfr[j][kk] = *(const bf16x8*)&Blds[row * 64 + (((kk * 4 + g) ^ sw) * 8)];
    }
    #pragma unroll
    for (int i = 0; i < 4; i++)
      #pragma unroll
      for (int j = 0; j < 4; j++)
        #pragma unroll
        for (int kk = 0; kk < 2; kk++)
          acc[i][j] = __builtin_amdgcn_mfma_f32_16x16x32_bf16(
              af[i][kk], bfr[j][kk], acc[i][j], 0, 0, 0);
    __syncthreads();
  }

  #pragma unroll
  for (int i = 0; i < 4; i++)
    #pragma unroll
    for (int j = 0; j < 4; j++)
      #pragma unroll
      for (int r = 0; r < 4; r++) {
        int m = m0 + wm + i * 16 + g * 4 + r;
        int n = n0 + wn + j * 16 + li;
        outf[(size_t)m * Dd + n] = acc[i][j][r] + bias[n];
      }
}

// ---------------------------------------------------------------- V GEMM (bf16 A, fp32 B, reg staging)
// V output bf16 TRANSPOSED [B,H,HD,T]
__global__ __launch_bounds__(256) void gemm_v(
    const short* __restrict__ Ab, const float* __restrict__ Wf,
    const float* __restrict__ bias, short* __restrict__ outb)
{
  constexpr int K = 1024;
  __shared__ short Alds[128][72];
  __shared__ short Blds[128][72];
  const int tid = threadIdx.x;
  const int lane = tid & 63, wave = tid >> 6;
  const int g = lane >> 4, li = lane & 15;
  const int m0 = blockIdx.x * 128, n0 = blockIdx.y * 128;
  const int wm = (wave >> 1) * 64, wn = (wave & 1) * 64;
  f32x4 acc[4][4] = {};

  for (int k0 = 0; k0 < K; k0 += 64) {
    #pragma unroll
    for (int s = 0; s < 4; s++) {
      int f = tid + s * 256; int row = f >> 3, c8 = f & 7;
      *(bf16x8*)&Alds[row][c8 * 8] =
          *(const bf16x8*)(Ab + (size_t)(m0 + row) * K + k0 + c8 * 8);
    }
    #pragma unroll
    for (int s = 0; s < 8; s++) {
      int f = tid + s * 256; int row = f >> 4, c4 = f & 15;
      float4 v = *(const float4*)(Wf + (size_t)(n0 + row) * K + k0 + c4 * 4);
      s16x4 p = { f2bf(v.x), f2bf(v.y), f2bf(v.z), f2bf(v.w) };
      *(s16x4*)&Blds[row][c4 * 4] = p;
    }
    __syncthreads();

    bf16x8 af[4][2], bfr[4][2];
    #pragma unroll
    for (int i = 0; i < 4; i++)
      #pragma unroll
      for (int kk = 0; kk < 2; kk++)
        af[i][kk] = *(const bf16x8*)&Alds[wm + i * 16 + li][kk * 32 + g * 8];
    #pragma unroll
    for (int j = 0; j < 4; j++)
      #pragma unroll
      for (int kk = 0; kk < 2; kk++)
        bfr[j][kk] = *(const bf16x8*)&Blds[wn + j * 16 + li][kk * 32 + g * 8];
    #pragma unroll
    for (int i = 0; i < 4; i++)
      #pragma unroll
      for (int j = 0; j < 4; j++)
        #pragma unroll
        for (int kk = 0; kk < 2; kk++)
          acc[i][j] = __builtin_amdgcn_mfma_f32_16x16x32_bf16(
              af[i][kk], bfr[j][kk], acc[i][j], 0, 0, 0);
    __syncthreads();
  }

  #pragma unroll
  for (int i = 0; i < 4; i++)
    #pragma unroll
    for (int j = 0; j < 4; j++) {
      int n = n0 + wn + j * 16 + li;
      s16x4 pk;
      #pragma unroll
      for (int r = 0; r < 4; r++) pk[r] = f2bf(acc[i][j][r] + bias[n]);
      int mb = m0 + wm + i * 16 + g * 4;
      int bI = mb >> 11, t0 = mb & (Tt - 1), h = n >> 6, d = n & (HD - 1);
      *(s16x4*)(outb + (((size_t)bI * Hh + h) * HD + d) * Tt + t0) = pk;
    }
}

// ---------------------------------------------------------------- attention
// Swapped-operand flash attention, 32x32x16 MFMA, 2 waves/block (64 q rows).
// grid (B*H, T/64). shfl_xor cross-lane (proven); + defer-max + max3 tree.
__device__ __forceinline__ void store_o(const f32x16& o, float inv,
                                        short* __restrict__ AO, size_t rowbase,
                                        int colbase, int h) {
  #pragma unroll
  for (int R = 0; R < 4; R++) {
    s16x4 pk;
    #pragma unroll
    for (int j = 0; j < 4; j++) pk[j] = f2bf(o[R * 4 + j] * inv);
    *(s16x4*)(AO + rowbase + colbase + 8 * R + 4 * h) = pk;
  }
}

__global__ __launch_bounds__(128, 4) void attn_k(
    const short* __restrict__ Qb, const short* __restrict__ Kb,
    const short* __restrict__ Vt_g, short* __restrict__ AO)
{
  __shared__ short Klds[64][72];
  __shared__ short Vt[64][72];      // row = d, col = kv
  const int tid = threadIdx.x, lane = tid & 63, wave = tid >> 6;
  const int h = lane >> 5;          // hi half-wave
  const int ql = lane & 31;         // this lane's q row (and A-frag row idx)
  const int bh = blockIdx.x;        // b*H + h  (fastest dim -> XCD-local K/V)
  const int q0 = blockIdx.y * 64 + wave * 32;
  const size_t base  = (size_t)bh * Tt * HD;   // Q,K layout
  const size_t basev = (size_t)bh * HD * Tt;   // V^T layout

  // Q B-fragments: col=q=lane&31, k = ks*16 + h*8 + e
  bf16x8 qf[4];
  #pragma unroll
  for (int ks = 0; ks < 4; ks++)
    qf[ks] = *(const bf16x8*)(Qb + base + (size_t)(q0 + ql) * HD + ks * 16 + h * 8);

  float m_i = -3.0e38f, l_i = 0.f;
  f32x16 o0 = {}, o1 = {};

  for (int kv0 = 0; kv0 < Tt; kv0 += 64) {
    #pragma unroll
    for (int s = 0; s < 4; s++) {
      int f = tid + s * 128; int row = f >> 3, c8 = f & 7;
      *(bf16x8*)&Klds[row][c8 * 8] =
          *(const bf16x8*)(Kb + base + (size_t)(kv0 + row) * HD + c8 * 8);
      *(bf16x8*)&Vt[row][c8 * 8] =
          *(const bf16x8*)(Vt_g + basev + (size_t)row * Tt + kv0 + c8 * 8);
    }
    __syncthreads();

    // S^T = K · Q^T, two 32-kv tiles. A-frag: row=kv=lane&31, k=ks*16+h*8+e.
    f32x16 st0 = {}, st1 = {};
    __builtin_amdgcn_s_setprio(1);
    #pragma unroll
    for (int ks = 0; ks < 4; ks++) {
      bf16x8 kf0 = *(const bf16x8*)&Klds[ql][ks * 16 + h * 8];
      bf16x8 kf1 = *(const bf16x8*)&Klds[32 + ql][ks * 16 + h * 8];
      st0 = __builtin_amdgcn_mfma_f32_32x32x16_bf16(kf0, qf[ks], st0, 0, 0, 0);
      st1 = __builtin_amdgcn_mfma_f32_32x32x16_bf16(kf1, qf[ks], st1, 0, 0, 0);
    }
    __builtin_amdgcn_s_setprio(0);
    // lane holds S'[kv = kvt*32 + (reg&3)+8*(reg>>2)+4h][q = ql], exp2 domain

    // row max: max3 tree over 32 in-lane values + cross-half shfl
    float t0 = max3f(st0[0],  st0[1],  st0[2]);
    float t1 = max3f(st0[3],  st0[4],  st0[5]);
    float t2 = max3f(st0[6],  st0[7],  st0[8]);
    float t3 = max3f(st0[9],  st0[10], st0[11]);
    float t4 = max3f(st0[12], st0[13], st0[14]);
    float t5 = max3f(st0[15], st1[0],  st1[1]);
    float t6 = max3f(st1[2],  st1[3],  st1[4]);
    float t7 = max3f(st1[5],  st1[6],  st1[7]);
    float t8 = max3f(st1[8],  st1[9],  st1[10]);
    float t9 = max3f(st1[11], st1[12], st1[13]);
    float ta = fmaxf(st1[14], st1[15]);
    float u0 = max3f(t0, t1, t2);
    float u1 = max3f(t3, t4, t5);
    float u2 = max3f(t6, t7, t8);
    float u3 = fmaxf(t9, ta);
    float mv = fmaxf(max3f(u0, u1, u2), u3);
    mv = fmaxf(mv, __shfl_xor(mv, 32, 64));

    // defer-max (T13): rescale only when max grew past threshold (exp2 domain)
    if (!__all(mv <= m_i + 8.0f)) {
      float mn = fmaxf(m_i, mv);
      float corr = __builtin_amdgcn_exp2f(m_i - mn);
      m_i = mn;
      l_i *= corr;
      #pragma unroll
      for (int r = 0; r < 16; r++) { o0[r] *= corr; o1[r] *= corr; }
    }

    // p = exp2(s - m) in place; row sum
    float rs = 0.f;
    #pragma unroll
    for (int r = 0; r < 16; r++) { st0[r] = __builtin_amdgcn_exp2f(st0[r] - m_i); rs += st0[r]; }
    #pragma unroll
    for (int r = 0; r < 16; r++) { st1[r] = __builtin_amdgcn_exp2f(st1[r] - m_i); rs += st1[r]; }
    rs += __shfl_xor(rs, 32, 64);
    l_i += rs;

    // PV: O^T += V^T · P^T. Per ks build P^T B-frag (col=q, k=ks*16+h*8+e)
    // from in-register p via pair-lane shfl exchange (round-6 proven).
    __builtin_amdgcn_s_setprio(1);
    #pragma unroll
    for (int ks = 0; ks < 4; ks++) {
      const int b0 = ((2 * ks) & 3) * 4;           // 0,8,0,8 (compile-time)
      float A0, A1, A2, A3, B0, B1, B2, B3;
      if (ks < 2) {
        A0 = st0[b0]; A1 = st0[b0 + 1]; A2 = st0[b0 + 2]; A3 = st0[b0 + 3];
        B0 = st0[b0 + 4]; B1 = st0[b0 + 5]; B2 = st0[b0 + 6]; B3 = st0[b0 + 7];
      } else {
        A0 = st1[b0]; A1 = st1[b0 + 1]; A2 = st1[b0 + 2]; A3 = st1[b0 + 3];
        B0 = st1[b0 + 4]; B1 = st1[b0 + 5]; B2 = st1[b0 + 6]; B3 = st1[b0 + 7];
      }
      // A* = group 2ks (e = j+4h), B* = group 2ks+1 (e = j+4h)
      unsigned wa0 = cvt_pk_bf16(A0, A1), wa1 = cvt_pk_bf16(A2, A3);
      unsigned wb0 = cvt_pk_bf16(B0, B1), wb1 = cvt_pk_bf16(B2, B3);
      // send group 2ks+(1-h); receive partner's group 2ks+h (e other half)
      unsigned s0 = h ? wa0 : wb0, s1 = h ? wa1 : wb1;
      unsigned r0 = (unsigned)__shfl_xor((int)s0, 32, 64);
      unsigned r1 = (unsigned)__shfl_xor((int)s1, 32, 64);
      unsigned own0 = h ? wb0 : wa0, own1 = h ? wb1 : wa1;
      union { unsigned u[4]; bf16x8 v; } pa;
      pa.u[0] = h ? r0 : own0;  pa.u[1] = h ? r1 : own1;
      pa.u[2] = h ? own0 : r0;  pa.u[3] = h ? own1 : r1;

      bf16x8 vf0 = *(const bf16x8*)&Vt[ql][ks * 16 + h * 8];
      bf16x8 vf1 = *(const bf16x8*)&Vt[32 + ql][ks * 16 + h * 8];
      o0 = __builtin_amdgcn_mfma_f32_32x32x16_bf16(vf0, pa.v, o0, 0, 0, 0);
      o1 = __builtin_amdgcn_mfma_f32_32x32x16_bf16(vf1, pa.v, o1, 0, 0, 0);
    }
    __builtin_amdgcn_s_setprio(0);
    __syncthreads();
  }

  // epilogue: O^T col = q = ql (per-lane l), row d = nt*32 + (reg&3)+8*(reg>>2)+4h
  float inv = 1.0f / l_i;
  const int b = bh >> 4, hh = bh & 15;
  size_t rowbase = ((size_t)b * Tt + q0 + ql) * Dd;
  store_o(o0, inv, AO, rowbase, hh * 64 + 0, h);
  store_o(o1, inv, AO, rowbase, hh * 64 + 32, h);
}

// ---------------------------------------------------------------- launch
// ws layout (65 MiB — proven-safe envelope):
//   [0, 512K) cs | [512K, 1M) sn
//   1M + [0, 16M)   Qb
//   1M + [16M,32M)  Kb   (Wob aliases its head after attn)
//   1M + [32M,48M)  Vb   (Wqb at +0, Wkb at +2M before gemm_v writes it)
//   1M + [48M,64M)  xb   (AO aliases after gemm_v consumed xb)
extern "C" void kernel_launch(void* const* d_in, const int* in_sizes, int n_in,
                              void* d_out, int out_size, void* d_ws, size_t ws_size,
                              hipStream_t stream)
{
  const float* x  = (const float*)d_in[0];
  const float* Wq = (const float*)d_in[1];
  const float* bq = (const float*)d_in[2];
  const float* Wk = (const float*)d_in[3];
  const float* bk = (const float*)d_in[4];
  const float* Wv = (const float*)d_in[5];
  const float* bv = (const float*)d_in[6];
  const float* Wo = (const float*)d_in[7];
  const float* bo = (const float*)d_in[8];
  float* out = (float*)d_out;

  char* ws = (char*)d_ws;
  float* cs = (float*)ws;
  float* sn = (float*)(ws + (size_t)(1 << 19));
  char*  p0 = ws + ((size_t)1 << 20);
  short* Qb = (short*)(p0);
  short* Kb = (short*)(p0 + ((size_t)16 << 20));
  short* Vb = (short*)(p0 + ((size_t)32 << 20));
  short* xb = (short*)(p0 + ((size_t)48 << 20));
  short* AO  = xb;                                  // xb dead after gemm_v
  short* Wqb = Vb;                                  // Vb dead until gemm_v writes
  short* Wkb = (short*)(p0 + ((size_t)34 << 20));   // Vb + 2MB
  short* Wob = Kb;                                  // Kb dead after attn

  cvt_k<<<dim3(Mm * Dd / 4 / 256), dim3(256), 0, stream>>>(x,  xb,  Mm * Dd / 4);
  cvt_k<<<dim3(Dd * Dd / 4 / 256), dim3(256), 0, stream>>>(Wq, Wqb, Dd * Dd / 4);
  cvt_k<<<dim3(Dd * Dd / 4 / 256), dim3(256), 0, stream>>>(Wk, Wkb, Dd * Dd / 4);
  rope_tab<<<dim3(512), dim3(256), 0, stream>>>(cs, sn);

  dim3 bb(256);
  gemm_qk<<<dim3(Mm / 128, Dd / 128, 2), bb, 0, stream>>>(
      xb, Wqb, Wkb, bq, bk, Qb, Kb, cs, sn);
  gemm_v<<<dim3(Mm / 128, Dd / 128), bb, 0, stream>>>(xb, Wv, bv, Vb);

  attn_k<<<dim3(Bb * Hh, Tt / 64), dim3(128), 0, stream>>>(Qb, Kb, Vb, AO);

  cvt_k<<<dim3(Dd * Dd / 4 / 256), dim3(256), 0, stream>>>(Wo, Wob, Dd * Dd / 4);
  gemm_fin<<<dim3(Mm / 128, Dd / 128), bb, 0, stream>>>(AO, Wob, bo, out);
}